// Round 1
// baseline (756.783 us; speedup 1.0000x reference)
//
#include <hip/hip_runtime.h>
#include <math.h>

// Problem constants (architecture dims are fixed by the model definition)
#define DIN 128
#define DH  32
#define H1  8
#define H2  2
#define GNUM 64
#define DOUT 10
#define NEG_SLOPE 0.2f

// ---------------------------------------------------------------------------
// CSR build: degree histogram (incl. self loops)
// ---------------------------------------------------------------------------
__global__ void k_deg(const int* __restrict__ dst, int* __restrict__ deg, int E, int n) {
    int i = blockIdx.x * blockDim.x + threadIdx.x;
    if (i < E) {
        atomicAdd(&deg[dst[i]], 1);
    } else if (i < E + n) {
        atomicAdd(&deg[i - E], 1);   // self loop
    }
}

// single-block exclusive scan over deg[0..n-1] -> offsets (in place), deg[n]=total
__global__ void k_scan(int* __restrict__ deg, int* __restrict__ cursor, int n) {
    __shared__ int buf[1024];
    __shared__ int carry_s;
    int tid = threadIdx.x;
    if (tid == 0) carry_s = 0;
    __syncthreads();
    for (int base = 0; base < n; base += 1024) {
        int i = base + tid;
        int val = (i < n) ? deg[i] : 0;
        buf[tid] = val;
        __syncthreads();
        for (int ofs = 1; ofs < 1024; ofs <<= 1) {
            int add = (tid >= ofs) ? buf[tid - ofs] : 0;
            __syncthreads();
            buf[tid] += add;
            __syncthreads();
        }
        int incl = buf[tid];
        int c = carry_s;
        __syncthreads();
        int excl = incl - val + c;
        if (i < n) { deg[i] = excl; cursor[i] = excl; }
        if (tid == 1023) carry_s = c + incl;
        __syncthreads();
    }
    if (tid == 0) deg[n] = carry_s;
}

__global__ void k_scatter(const int* __restrict__ src, const int* __restrict__ dst,
                          int* __restrict__ cursor, int* __restrict__ csr_src, int E, int n) {
    int i = blockIdx.x * blockDim.x + threadIdx.x;
    if (i < E) {
        int d = dst[i];
        int pos = atomicAdd(&cursor[d], 1);
        csr_src[pos] = src[i];
    } else if (i < E + n) {
        int v = i - E;
        int pos = atomicAdd(&cursor[v], 1);
        csr_src[pos] = v;   // self loop: src == dst
    }
}

// ---------------------------------------------------------------------------
// Dual GEMM: C[M, 2*Nh] = A[M,K] @ [B1 | B2]   (row-major, fp32, LDS-tiled)
// 64x64 tile, 256 threads, 4x4 micro-tile
// ---------------------------------------------------------------------------
__global__ __launch_bounds__(256)
void k_gemm_dual(const float* __restrict__ A, const float* __restrict__ B1,
                 const float* __restrict__ B2, float* __restrict__ C,
                 int M, int K, int Nh) {
    __shared__ float As[16][65];
    __shared__ float Bs[16][64];
    const int m0  = blockIdx.x * 64;
    const int n0g = blockIdx.y * 64;                  // global col in [0, 2*Nh)
    const float* B = (n0g < Nh) ? B1 : B2;
    const int n0   = (n0g < Nh) ? n0g : (n0g - Nh);
    const int tid = threadIdx.x;
    const int tx = tid & 15, ty = tid >> 4;
    float acc[4][4] = {};

    for (int kt = 0; kt < K; kt += 16) {
        {   // A tile: 64 rows x 16 k
            int r  = tid >> 2;
            int kk = (tid & 3) * 4;
            int mg = m0 + r;
            float4 v = make_float4(0.f, 0.f, 0.f, 0.f);
            if (mg < M) v = *(const float4*)(A + (size_t)mg * K + kt + kk);
            As[kk + 0][r] = v.x; As[kk + 1][r] = v.y;
            As[kk + 2][r] = v.z; As[kk + 3][r] = v.w;
        }
        {   // B tile: 16 k x 64 n
            int kk = tid >> 4;
            int nn = (tid & 15) * 4;
            float4 v = *(const float4*)(B + (size_t)(kt + kk) * Nh + n0 + nn);
            *(float4*)&Bs[kk][nn] = v;
        }
        __syncthreads();
        #pragma unroll
        for (int k = 0; k < 16; ++k) {
            float a[4], b[4];
            #pragma unroll
            for (int i = 0; i < 4; ++i) a[i] = As[k][ty * 4 + i];
            #pragma unroll
            for (int j = 0; j < 4; ++j) b[j] = Bs[k][tx * 4 + j];
            #pragma unroll
            for (int i = 0; i < 4; ++i)
                #pragma unroll
                for (int j = 0; j < 4; ++j)
                    acc[i][j] = fmaf(a[i], b[j], acc[i][j]);
        }
        __syncthreads();
    }
    const int ldc = 2 * Nh;
    #pragma unroll
    for (int i = 0; i < 4; ++i) {
        int mg = m0 + ty * 4 + i;
        if (mg < M) {
            float4 v = make_float4(acc[i][0], acc[i][1], acc[i][2], acc[i][3]);
            *(float4*)(C + (size_t)mg * ldc + n0g + tx * 4) = v;
        }
    }
}

// ---------------------------------------------------------------------------
// Fused GATv2 edge pass with online softmax. One wave per node.
// XLR rows: [ xl (P*64 ch) | xr (P*64 ch) ], stride P*128.
// Lane c = p*64 + lane maps to head h = c/32, dim d = c%32.
// ---------------------------------------------------------------------------
template<int P, bool DO_ELU>
__global__ __launch_bounds__(256)
void k_gat_edge(const float* __restrict__ XLR,
                const int* __restrict__ offs, const int* __restrict__ csr_src,
                const float* __restrict__ att, const float* __restrict__ bias,
                float* __restrict__ out, int n) {
    const int lane = threadIdx.x & 63;
    const int wid  = threadIdx.x >> 6;
    const int v = blockIdx.x * (blockDim.x >> 6) + wid;
    if (v >= n) return;
    const int stride = P * 128;

    float xr[P], av[P], m[P], z[P], acc[P];
    const float* xrrow = XLR + (size_t)v * stride + P * 64;
    #pragma unroll
    for (int p = 0; p < P; ++p) {
        xr[p]  = xrrow[p * 64 + lane];
        av[p]  = att[p * 64 + lane];
        m[p]   = -INFINITY;
        z[p]   = 0.f;
        acc[p] = 0.f;
    }
    const int e0 = offs[v], e1 = offs[v + 1];
    for (int j = e0; j < e1; ++j) {
        const int src = csr_src[j];
        const float* xlrow = XLR + (size_t)src * stride;
        #pragma unroll
        for (int p = 0; p < P; ++p) {
            float xlv = xlrow[p * 64 + lane];
            float t = xlv + xr[p];
            t = (t > 0.f) ? t : NEG_SLOPE * t;
            float s = t * av[p];
            s += __shfl_xor(s, 16);
            s += __shfl_xor(s, 8);
            s += __shfl_xor(s, 4);
            s += __shfl_xor(s, 2);
            s += __shfl_xor(s, 1);
            float nm = fmaxf(m[p], s);
            float sc = __expf(m[p] - nm);
            float w  = __expf(s - nm);
            z[p]   = z[p] * sc + w;
            acc[p] = acc[p] * sc + w * xlv;
            m[p]   = nm;
        }
    }
    #pragma unroll
    for (int p = 0; p < P; ++p) {
        float o = acc[p] / z[p] + bias[p * 64 + lane];
        if (DO_ELU) o = (o > 0.f) ? o : (__expf(o) - 1.f);
        out[(size_t)v * (P * 64) + p * 64 + lane] = o;
    }
}

// ---------------------------------------------------------------------------
// Global mean pool (sum + count via atomics)
// ---------------------------------------------------------------------------
__global__ void k_pool(const float* __restrict__ out2, const int* __restrict__ batch,
                       float* __restrict__ gsum, float* __restrict__ gcnt, int n) {
    int i = blockIdx.x * blockDim.x + threadIdx.x;
    if (i >= n * 64) return;
    int v = i >> 6, c = i & 63;
    int g = batch[v];
    atomicAdd(&gsum[g * 64 + c], out2[i]);
    if (c == 0) atomicAdd(&gcnt[g], 1.0f);
}

// ---------------------------------------------------------------------------
// MLP head: one thread per graph
// ---------------------------------------------------------------------------
__global__ void k_mlp(const float* __restrict__ gsum, const float* __restrict__ gcnt,
                      const float* __restrict__ fc1w, const float* __restrict__ fc1b,
                      const float* __restrict__ fc2w, const float* __restrict__ fc2b,
                      const float* __restrict__ fcw,  const float* __restrict__ fcb,
                      float* __restrict__ outc, float* __restrict__ outx2) {
    int g = threadIdx.x;
    if (g >= GNUM) return;
    float cnt = fmaxf(gcnt[g], 1.0f);
    float hg[64];
    #pragma unroll
    for (int k = 0; k < 64; ++k) hg[k] = gsum[g * 64 + k] / cnt;
    float x1[32];
    for (int j = 0; j < 32; ++j) {
        float s = fc1b[j];
        for (int k = 0; k < 64; ++k) s = fmaf(hg[k], fc1w[k * 32 + j], s);
        x1[j] = fmaxf(s, 0.f);
    }
    float x2[16];
    for (int j = 0; j < 16; ++j) {
        float s = fc2b[j];
        for (int k = 0; k < 32; ++k) s = fmaf(x1[k], fc2w[k * 16 + j], s);
        x2[j] = fmaxf(s, 0.f);
    }
    for (int j = 0; j < DOUT; ++j) {
        float s = fcb[j];
        for (int k = 0; k < 16; ++k) s = fmaf(x2[k], fcw[k * 10 + j], s);
        outc[g * DOUT + j] = s;
    }
    for (int j = 0; j < 16; ++j) outx2[g * 16 + j] = x2[j];
}

// ---------------------------------------------------------------------------
extern "C" void kernel_launch(void* const* d_in, const int* in_sizes, int n_in,
                              void* d_out, int out_size, void* d_ws, size_t ws_size,
                              hipStream_t stream) {
    const float* x    = (const float*)d_in[0];
    const int*   ei   = (const int*)d_in[1];
    const int*   batch= (const int*)d_in[2];
    const float* W1l  = (const float*)d_in[3];
    const float* W1r  = (const float*)d_in[4];
    const float* a1   = (const float*)d_in[5];
    const float* b1   = (const float*)d_in[6];
    const float* W2l  = (const float*)d_in[7];
    const float* W2r  = (const float*)d_in[8];
    const float* a2   = (const float*)d_in[9];
    const float* b2   = (const float*)d_in[10];
    const float* fc1w = (const float*)d_in[11];
    const float* fc1b = (const float*)d_in[12];
    const float* fc2w = (const float*)d_in[13];
    const float* fc2b = (const float*)d_in[14];
    const float* fcw  = (const float*)d_in[15];
    const float* fcb  = (const float*)d_in[16];

    const int N = in_sizes[2];          // 30000
    const int E = in_sizes[1] / 2;      // 480000
    const int ET = E + N;
    const int* esrc = ei;
    const int* edst = ei + E;

    // workspace layout (bytes)
    char* ws = (char*)d_ws;
    size_t off = 0;
    float* xlr1 = (float*)(ws + off);            off += (size_t)N * 512 * 4;   // [N,512]: xl1|xr1
    float* h1   = (float*)(ws + off);            off += (size_t)N * 256 * 4;   // [N,256]
    size_t off_csrbase = off;
    int*   deg   = (int*)(ws + off);             off += ((size_t)(N + 1) * 4 + 255) & ~255ull;
    int*   cursor= (int*)(ws + off);             off += ((size_t)N * 4 + 255) & ~255ull;
    int*   csr   = (int*)(ws + off);             off += ((size_t)ET * 4 + 255) & ~255ull;
    float* gsum  = (float*)(ws + off);           off += (size_t)GNUM * 64 * 4;
    float* gcnt  = (float*)(ws + off);           off += (size_t)GNUM * 4;
    // layer-2 buffers reuse the xlr1 region (free after edge pass 1)
    float* xlr2 = xlr1;                                   // [N,128]: xl2|xr2
    float* out2 = xlr1 + (size_t)N * 128;                 // [N,64]
    (void)off_csrbase; (void)ws_size; (void)n_in; (void)out_size;

    float* outc  = (float*)d_out;            // [64,10]
    float* outx2 = (float*)d_out + GNUM * DOUT;  // [64,16]

    // zero the accumulators / histogram
    hipMemsetAsync(deg, 0, (size_t)(N + 1) * 4, stream);
    hipMemsetAsync(gsum, 0, (size_t)GNUM * 64 * 4, stream);
    hipMemsetAsync(gcnt, 0, (size_t)GNUM * 4, stream);

    // CSR build
    int tb = 256;
    int gb = (ET + tb - 1) / tb;
    k_deg<<<gb, tb, 0, stream>>>(edst, deg, E, N);
    k_scan<<<1, 1024, 0, stream>>>(deg, cursor, N);
    k_scatter<<<gb, tb, 0, stream>>>(esrc, edst, cursor, csr, E, N);

    // Layer 1: xl1|xr1 = x @ [W1l|W1r]   (M=N, K=128, Nh=256)
    dim3 g1((N + 63) / 64, 8);
    k_gemm_dual<<<g1, 256, 0, stream>>>(x, W1l, W1r, xlr1, N, DIN, 256);

    // Layer 1 edge pass + bias + ELU -> h1 [N,256]
    k_gat_edge<4, true><<<(N + 3) / 4, 256, 0, stream>>>(xlr1, deg, csr, a1, b1, h1, N);

    // Layer 2: xl2|xr2 = h1 @ [W2l|W2r]  (M=N, K=256, Nh=64)
    dim3 g2((N + 63) / 64, 2);
    k_gemm_dual<<<g2, 256, 0, stream>>>(h1, W2l, W2r, xlr2, N, 256, 64);

    // Layer 2 edge pass + bias -> out2 [N,64]
    k_gat_edge<1, false><<<(N + 3) / 4, 256, 0, stream>>>(xlr2, deg, csr, a2, b2, out2, N);

    // Pool
    k_pool<<<(N * 64 + 255) / 256, 256, 0, stream>>>(out2, batch, gsum, gcnt, N);

    // MLP head
    k_mlp<<<1, 64, 0, stream>>>(gsum, gcnt, fc1w, fc1b, fc2w, fc2b, fcw, fcb, outc, outx2);
}

// Round 2
// 569.988 us; speedup vs baseline: 1.3277x; 1.3277x over previous
//
#include <hip/hip_runtime.h>
#include <math.h>

// Problem constants (architecture dims are fixed by the model definition)
#define DIN 128
#define DH  32
#define H1  8
#define H2  2
#define GNUM 64
#define DOUT 10
#define NEG_SLOPE 0.2f

// ---------------------------------------------------------------------------
// CSR build: degree histogram (incl. self loops)
// ---------------------------------------------------------------------------
__global__ void k_deg(const int* __restrict__ dst, int* __restrict__ deg, int E, int n) {
    int i = blockIdx.x * blockDim.x + threadIdx.x;
    if (i < E) {
        atomicAdd(&deg[dst[i]], 1);
    } else if (i < E + n) {
        atomicAdd(&deg[i - E], 1);   // self loop
    }
}

// single-block exclusive scan over deg[0..n-1] -> offsets (in place), deg[n]=total
__global__ void k_scan(int* __restrict__ deg, int* __restrict__ cursor, int n) {
    __shared__ int buf[1024];
    __shared__ int carry_s;
    int tid = threadIdx.x;
    if (tid == 0) carry_s = 0;
    __syncthreads();
    for (int base = 0; base < n; base += 1024) {
        int i = base + tid;
        int val = (i < n) ? deg[i] : 0;
        buf[tid] = val;
        __syncthreads();
        for (int ofs = 1; ofs < 1024; ofs <<= 1) {
            int add = (tid >= ofs) ? buf[tid - ofs] : 0;
            __syncthreads();
            buf[tid] += add;
            __syncthreads();
        }
        int incl = buf[tid];
        int c = carry_s;
        __syncthreads();
        int excl = incl - val + c;
        if (i < n) { deg[i] = excl; cursor[i] = excl; }
        if (tid == 1023) carry_s = c + incl;
        __syncthreads();
    }
    if (tid == 0) deg[n] = carry_s;
}

__global__ void k_scatter(const int* __restrict__ src, const int* __restrict__ dst,
                          int* __restrict__ cursor, int* __restrict__ csr_src, int E, int n) {
    int i = blockIdx.x * blockDim.x + threadIdx.x;
    if (i < E) {
        int d = dst[i];
        int pos = atomicAdd(&cursor[d], 1);
        csr_src[pos] = src[i];
    } else if (i < E + n) {
        int v = i - E;
        int pos = atomicAdd(&cursor[v], 1);
        csr_src[pos] = v;   // self loop: src == dst
    }
}

// ---------------------------------------------------------------------------
// Dual GEMM: C[M, 2*Nh] = A[M,K] @ [B1 | B2]   (row-major, fp32, LDS-tiled)
// 64x64 tile, 256 threads, 4x4 micro-tile
// ---------------------------------------------------------------------------
__global__ __launch_bounds__(256)
void k_gemm_dual(const float* __restrict__ A, const float* __restrict__ B1,
                 const float* __restrict__ B2, float* __restrict__ C,
                 int M, int K, int Nh) {
    __shared__ float As[16][65];
    __shared__ float Bs[16][64];
    const int m0  = blockIdx.x * 64;
    const int n0g = blockIdx.y * 64;                  // global col in [0, 2*Nh)
    const float* B = (n0g < Nh) ? B1 : B2;
    const int n0   = (n0g < Nh) ? n0g : (n0g - Nh);
    const int tid = threadIdx.x;
    const int tx = tid & 15, ty = tid >> 4;
    float acc[4][4] = {};

    for (int kt = 0; kt < K; kt += 16) {
        {   // A tile: 64 rows x 16 k
            int r  = tid >> 2;
            int kk = (tid & 3) * 4;
            int mg = m0 + r;
            float4 v = make_float4(0.f, 0.f, 0.f, 0.f);
            if (mg < M) v = *(const float4*)(A + (size_t)mg * K + kt + kk);
            As[kk + 0][r] = v.x; As[kk + 1][r] = v.y;
            As[kk + 2][r] = v.z; As[kk + 3][r] = v.w;
        }
        {   // B tile: 16 k x 64 n
            int kk = tid >> 4;
            int nn = (tid & 15) * 4;
            float4 v = *(const float4*)(B + (size_t)(kt + kk) * Nh + n0 + nn);
            *(float4*)&Bs[kk][nn] = v;
        }
        __syncthreads();
        #pragma unroll
        for (int k = 0; k < 16; ++k) {
            float a[4], b[4];
            #pragma unroll
            for (int i = 0; i < 4; ++i) a[i] = As[k][ty * 4 + i];
            #pragma unroll
            for (int j = 0; j < 4; ++j) b[j] = Bs[k][tx * 4 + j];
            #pragma unroll
            for (int i = 0; i < 4; ++i)
                #pragma unroll
                for (int j = 0; j < 4; ++j)
                    acc[i][j] = fmaf(a[i], b[j], acc[i][j]);
        }
        __syncthreads();
    }
    const int ldc = 2 * Nh;
    #pragma unroll
    for (int i = 0; i < 4; ++i) {
        int mg = m0 + ty * 4 + i;
        if (mg < M) {
            float4 v = make_float4(acc[i][0], acc[i][1], acc[i][2], acc[i][3]);
            *(float4*)(C + (size_t)mg * ldc + n0g + tx * 4) = v;
        }
    }
}

// ---------------------------------------------------------------------------
// Fused GATv2 edge pass with online softmax. One wave per node.
// XLR rows: [ xl (P*64 ch) | xr (P*64 ch) ], stride P*128.
// Lane c = p*64 + lane maps to head h = c/32, dim d = c%32.
// ---------------------------------------------------------------------------
template<int P, bool DO_ELU>
__global__ __launch_bounds__(256)
void k_gat_edge(const float* __restrict__ XLR,
                const int* __restrict__ offs, const int* __restrict__ csr_src,
                const float* __restrict__ att, const float* __restrict__ bias,
                float* __restrict__ out, int n) {
    const int lane = threadIdx.x & 63;
    const int wid  = threadIdx.x >> 6;
    const int v = blockIdx.x * (blockDim.x >> 6) + wid;
    if (v >= n) return;
    const int stride = P * 128;

    float xr[P], av[P], m[P], z[P], acc[P];
    const float* xrrow = XLR + (size_t)v * stride + P * 64;
    #pragma unroll
    for (int p = 0; p < P; ++p) {
        xr[p]  = xrrow[p * 64 + lane];
        av[p]  = att[p * 64 + lane];
        m[p]   = -INFINITY;
        z[p]   = 0.f;
        acc[p] = 0.f;
    }
    const int e0 = offs[v], e1 = offs[v + 1];
    for (int j = e0; j < e1; ++j) {
        const int src = csr_src[j];
        const float* xlrow = XLR + (size_t)src * stride;
        #pragma unroll
        for (int p = 0; p < P; ++p) {
            float xlv = xlrow[p * 64 + lane];
            float t = xlv + xr[p];
            t = (t > 0.f) ? t : NEG_SLOPE * t;
            float s = t * av[p];
            s += __shfl_xor(s, 16);
            s += __shfl_xor(s, 8);
            s += __shfl_xor(s, 4);
            s += __shfl_xor(s, 2);
            s += __shfl_xor(s, 1);
            float nm = fmaxf(m[p], s);
            float sc = __expf(m[p] - nm);
            float w  = __expf(s - nm);
            z[p]   = z[p] * sc + w;
            acc[p] = acc[p] * sc + w * xlv;
            m[p]   = nm;
        }
    }
    #pragma unroll
    for (int p = 0; p < P; ++p) {
        float o = acc[p] / z[p] + bias[p * 64 + lane];
        if (DO_ELU) o = (o > 0.f) ? o : (__expf(o) - 1.f);
        out[(size_t)v * (P * 64) + p * 64 + lane] = o;
    }
}

// ---------------------------------------------------------------------------
// Global mean pool: one block per graph, no atomics.
// batch is sorted, so graph g owns contiguous node range [lo, hi) found by
// binary search. lane = channel (64), 4 waves stride over nodes, LDS-reduce.
// Writes hg[g][c] = mean (division folded in here).
// ---------------------------------------------------------------------------
__global__ __launch_bounds__(256)
void k_pool(const float* __restrict__ out2, const int* __restrict__ batch,
            float* __restrict__ hg, int n) {
    const int g = blockIdx.x;
    const int lane = threadIdx.x & 63;
    const int w = threadIdx.x >> 6;
    // lower_bound(batch, g) and lower_bound(batch, g+1)
    int lo = 0, hi = n;
    while (lo < hi) { int mid = (lo + hi) >> 1; if (batch[mid] < g) lo = mid + 1; else hi = mid; }
    const int start = lo;
    hi = n;
    while (lo < hi) { int mid = (lo + hi) >> 1; if (batch[mid] < g + 1) lo = mid + 1; else hi = mid; }
    const int end = lo;

    float s = 0.f;
    for (int v = start + w; v < end; v += 4)
        s += out2[(size_t)v * 64 + lane];
    __shared__ float red[4][64];
    red[w][lane] = s;
    __syncthreads();
    if (w == 0) {
        float tot = red[0][lane] + red[1][lane] + red[2][lane] + red[3][lane];
        float cnt = fmaxf((float)(end - start), 1.0f);
        hg[g * 64 + lane] = tot / cnt;
    }
}

// ---------------------------------------------------------------------------
// MLP head: one thread per graph (reads hg = pooled means directly)
// ---------------------------------------------------------------------------
__global__ void k_mlp(const float* __restrict__ hgbuf,
                      const float* __restrict__ fc1w, const float* __restrict__ fc1b,
                      const float* __restrict__ fc2w, const float* __restrict__ fc2b,
                      const float* __restrict__ fcw,  const float* __restrict__ fcb,
                      float* __restrict__ outc, float* __restrict__ outx2) {
    int g = threadIdx.x;
    if (g >= GNUM) return;
    float hg[64];
    #pragma unroll
    for (int k = 0; k < 64; ++k) hg[k] = hgbuf[g * 64 + k];
    float x1[32];
    for (int j = 0; j < 32; ++j) {
        float s = fc1b[j];
        for (int k = 0; k < 64; ++k) s = fmaf(hg[k], fc1w[k * 32 + j], s);
        x1[j] = fmaxf(s, 0.f);
    }
    float x2[16];
    for (int j = 0; j < 16; ++j) {
        float s = fc2b[j];
        for (int k = 0; k < 32; ++k) s = fmaf(x1[k], fc2w[k * 16 + j], s);
        x2[j] = fmaxf(s, 0.f);
    }
    for (int j = 0; j < DOUT; ++j) {
        float s = fcb[j];
        for (int k = 0; k < 16; ++k) s = fmaf(x2[k], fcw[k * 10 + j], s);
        outc[g * DOUT + j] = s;
    }
    for (int j = 0; j < 16; ++j) outx2[g * 16 + j] = x2[j];
}

// ---------------------------------------------------------------------------
extern "C" void kernel_launch(void* const* d_in, const int* in_sizes, int n_in,
                              void* d_out, int out_size, void* d_ws, size_t ws_size,
                              hipStream_t stream) {
    const float* x    = (const float*)d_in[0];
    const int*   ei   = (const int*)d_in[1];
    const int*   batch= (const int*)d_in[2];
    const float* W1l  = (const float*)d_in[3];
    const float* W1r  = (const float*)d_in[4];
    const float* a1   = (const float*)d_in[5];
    const float* b1   = (const float*)d_in[6];
    const float* W2l  = (const float*)d_in[7];
    const float* W2r  = (const float*)d_in[8];
    const float* a2   = (const float*)d_in[9];
    const float* b2   = (const float*)d_in[10];
    const float* fc1w = (const float*)d_in[11];
    const float* fc1b = (const float*)d_in[12];
    const float* fc2w = (const float*)d_in[13];
    const float* fc2b = (const float*)d_in[14];
    const float* fcw  = (const float*)d_in[15];
    const float* fcb  = (const float*)d_in[16];

    const int N = in_sizes[2];          // 30000
    const int E = in_sizes[1] / 2;      // 480000
    const int ET = E + N;
    const int* esrc = ei;
    const int* edst = ei + E;

    // workspace layout (bytes)
    char* ws = (char*)d_ws;
    size_t off = 0;
    float* xlr1 = (float*)(ws + off);            off += (size_t)N * 512 * 4;   // [N,512]: xl1|xr1
    float* h1   = (float*)(ws + off);            off += (size_t)N * 256 * 4;   // [N,256]
    int*   deg   = (int*)(ws + off);             off += ((size_t)(N + 1) * 4 + 255) & ~255ull;
    int*   cursor= (int*)(ws + off);             off += ((size_t)N * 4 + 255) & ~255ull;
    int*   csr   = (int*)(ws + off);             off += ((size_t)ET * 4 + 255) & ~255ull;
    float* hgbuf = (float*)(ws + off);           off += (size_t)GNUM * 64 * 4;
    // layer-2 buffers reuse the xlr1 region (free after edge pass 1)
    float* xlr2 = xlr1;                                   // [N,128]: xl2|xr2
    float* out2 = xlr1 + (size_t)N * 128;                 // [N,64]
    (void)ws_size; (void)n_in; (void)out_size;

    float* outc  = (float*)d_out;                // [64,10]
    float* outx2 = (float*)d_out + GNUM * DOUT;  // [64,16]

    // zero the histogram
    hipMemsetAsync(deg, 0, (size_t)(N + 1) * 4, stream);

    // CSR build
    int tb = 256;
    int gb = (ET + tb - 1) / tb;
    k_deg<<<gb, tb, 0, stream>>>(edst, deg, E, N);
    k_scan<<<1, 1024, 0, stream>>>(deg, cursor, N);
    k_scatter<<<gb, tb, 0, stream>>>(esrc, edst, cursor, csr, E, N);

    // Layer 1: xl1|xr1 = x @ [W1l|W1r]   (M=N, K=128, Nh=256)
    dim3 g1((N + 63) / 64, 8);
    k_gemm_dual<<<g1, 256, 0, stream>>>(x, W1l, W1r, xlr1, N, DIN, 256);

    // Layer 1 edge pass + bias + ELU -> h1 [N,256]
    k_gat_edge<4, true><<<(N + 3) / 4, 256, 0, stream>>>(xlr1, deg, csr, a1, b1, h1, N);

    // Layer 2: xl2|xr2 = h1 @ [W2l|W2r]  (M=N, K=256, Nh=64)
    dim3 g2((N + 63) / 64, 2);
    k_gemm_dual<<<g2, 256, 0, stream>>>(h1, W2l, W2r, xlr2, N, 256, 64);

    // Layer 2 edge pass + bias -> out2 [N,64]
    k_gat_edge<1, false><<<(N + 3) / 4, 256, 0, stream>>>(xlr2, deg, csr, a2, b2, out2, N);

    // Pool (no atomics: one block per graph, binary-search node range)
    k_pool<<<GNUM, 256, 0, stream>>>(out2, batch, hgbuf, N);

    // MLP head
    k_mlp<<<1, 64, 0, stream>>>(hgbuf, fc1w, fc1b, fc2w, fc2b, fcw, fcb, outc, outx2);
}

// Round 3
// 449.431 us; speedup vs baseline: 1.6839x; 1.2682x over previous
//
#include <hip/hip_runtime.h>
#include <math.h>

#define DIN 128
#define DH  32
#define H1  8
#define H2  2
#define GNUM 64
#define DOUT 10
#define NEG_SLOPE 0.2f
#define SCAN_B 512

// ---------------------------------------------------------------------------
// CSR build: degree histogram (incl. self loops)
// ---------------------------------------------------------------------------
__global__ void k_deg(const int* __restrict__ dst, int* __restrict__ deg, int E, int n) {
    int i = blockIdx.x * blockDim.x + threadIdx.x;
    if (i < E) {
        atomicAdd(&deg[dst[i]], 1);
    } else if (i < E + n) {
        atomicAdd(&deg[i - E], 1);   // self loop
    }
}

// 3-phase parallel exclusive scan over deg[0..n-1] (in place), deg[n] = total
__global__ __launch_bounds__(SCAN_B)
void k_scan_partial(const int* __restrict__ deg, int* __restrict__ bsum, int n) {
    int i = blockIdx.x * SCAN_B + threadIdx.x;
    int v = (i < n) ? deg[i] : 0;
    #pragma unroll
    for (int m = 32; m >= 1; m >>= 1) v += __shfl_xor(v, m);
    __shared__ int red[SCAN_B / 64];
    if ((threadIdx.x & 63) == 0) red[threadIdx.x >> 6] = v;
    __syncthreads();
    if (threadIdx.x == 0) {
        int s = 0;
        #pragma unroll
        for (int k = 0; k < SCAN_B / 64; ++k) s += red[k];
        bsum[blockIdx.x] = s;
    }
}

__global__ void k_scan_bsum(int* __restrict__ bsum, int nb) {
    if (threadIdx.x == 0 && blockIdx.x == 0) {
        int run = 0;
        for (int k = 0; k < nb; ++k) { int t = bsum[k]; bsum[k] = run; run += t; }
        bsum[nb] = run;
    }
}

__global__ __launch_bounds__(SCAN_B)
void k_scan_apply(int* __restrict__ deg, int* __restrict__ cursor,
                  const int* __restrict__ bsum, int n, int nb) {
    __shared__ int buf[SCAN_B];
    int t = threadIdx.x, b = blockIdx.x;
    int i = b * SCAN_B + t;
    int v = (i < n) ? deg[i] : 0;
    buf[t] = v;
    __syncthreads();
    for (int o = 1; o < SCAN_B; o <<= 1) {
        int a = (t >= o) ? buf[t - o] : 0;
        __syncthreads();
        buf[t] += a;
        __syncthreads();
    }
    int excl = buf[t] - v + bsum[b];
    if (i < n) { deg[i] = excl; cursor[i] = excl; }
    if (b == 0 && t == 0) deg[n] = bsum[nb];
}

__global__ void k_scatter(const int* __restrict__ src, const int* __restrict__ dst,
                          int* __restrict__ cursor, int* __restrict__ csr_src, int E, int n) {
    int i = blockIdx.x * blockDim.x + threadIdx.x;
    if (i < E) {
        int d = dst[i];
        int pos = atomicAdd(&cursor[d], 1);
        csr_src[pos] = src[i];
    } else if (i < E + n) {
        int v = i - E;
        int pos = atomicAdd(&cursor[v], 1);
        csr_src[pos] = v;   // self loop
    }
}

// ---------------------------------------------------------------------------
// Dual GEMM: C[M, 2*Nh] = A[M,K] @ [B1 | B2]   (row-major, fp32, LDS-tiled)
// ---------------------------------------------------------------------------
__global__ __launch_bounds__(256)
void k_gemm_dual(const float* __restrict__ A, const float* __restrict__ B1,
                 const float* __restrict__ B2, float* __restrict__ C,
                 int M, int K, int Nh) {
    __shared__ float As[16][65];
    __shared__ float Bs[16][64];
    const int m0  = blockIdx.x * 64;
    const int n0g = blockIdx.y * 64;
    const float* B = (n0g < Nh) ? B1 : B2;
    const int n0   = (n0g < Nh) ? n0g : (n0g - Nh);
    const int tid = threadIdx.x;
    const int tx = tid & 15, ty = tid >> 4;
    float acc[4][4] = {};

    for (int kt = 0; kt < K; kt += 16) {
        {
            int r  = tid >> 2;
            int kk = (tid & 3) * 4;
            int mg = m0 + r;
            float4 v = make_float4(0.f, 0.f, 0.f, 0.f);
            if (mg < M) v = *(const float4*)(A + (size_t)mg * K + kt + kk);
            As[kk + 0][r] = v.x; As[kk + 1][r] = v.y;
            As[kk + 2][r] = v.z; As[kk + 3][r] = v.w;
        }
        {
            int kk = tid >> 4;
            int nn = (tid & 15) * 4;
            float4 v = *(const float4*)(B + (size_t)(kt + kk) * Nh + n0 + nn);
            *(float4*)&Bs[kk][nn] = v;
        }
        __syncthreads();
        #pragma unroll
        for (int k = 0; k < 16; ++k) {
            float a[4], b[4];
            #pragma unroll
            for (int i = 0; i < 4; ++i) a[i] = As[k][ty * 4 + i];
            #pragma unroll
            for (int j = 0; j < 4; ++j) b[j] = Bs[k][tx * 4 + j];
            #pragma unroll
            for (int i = 0; i < 4; ++i)
                #pragma unroll
                for (int j = 0; j < 4; ++j)
                    acc[i][j] = fmaf(a[i], b[j], acc[i][j]);
        }
        __syncthreads();
    }
    const int ldc = 2 * Nh;
    #pragma unroll
    for (int i = 0; i < 4; ++i) {
        int mg = m0 + ty * 4 + i;
        if (mg < M) {
            float4 v = make_float4(acc[i][0], acc[i][1], acc[i][2], acc[i][3]);
            *(float4*)(C + (size_t)mg * ldc + n0g + tx * 4) = v;
        }
    }
}

// ---------------------------------------------------------------------------
// Layer-1 edge pass: one wave per node, float4 per lane (256 ch).
// lane l owns dims 4l..4l+3; head = l/8 (8 heads x 32 dims).
// Scores are O(1) magnitude (glorot att) -> plain exp, no max tracking.
// ---------------------------------------------------------------------------
__global__ __launch_bounds__(256)
void k_edge1(const float* __restrict__ XLR, const int* __restrict__ offs,
             const int* __restrict__ csr, const float* __restrict__ att,
             const float* __restrict__ bias, float* __restrict__ out, int n) {
    const int lane = threadIdx.x & 63;
    const int wid  = threadIdx.x >> 6;
    const int v = blockIdx.x * 4 + wid;
    if (v >= n) return;
    const float4 xr = *(const float4*)(XLR + (size_t)v * 512 + 256 + lane * 4);
    const float4 av = *(const float4*)(att + lane * 4);
    const float4 bv = *(const float4*)(bias + lane * 4);
    float z = 0.f;
    float4 acc = make_float4(0.f, 0.f, 0.f, 0.f);
    const int e0 = offs[v], e1 = offs[v + 1];
    for (int j = e0; j < e1; ++j) {
        const int src = csr[j];
        const float4 xl = *(const float4*)(XLR + (size_t)src * 512 + lane * 4);
        float tx = xl.x + xr.x, ty = xl.y + xr.y, tz = xl.z + xr.z, tw = xl.w + xr.w;
        float lx = fmaxf(tx, 0.f) + NEG_SLOPE * fminf(tx, 0.f);
        float ly = fmaxf(ty, 0.f) + NEG_SLOPE * fminf(ty, 0.f);
        float lz = fmaxf(tz, 0.f) + NEG_SLOPE * fminf(tz, 0.f);
        float lw = fmaxf(tw, 0.f) + NEG_SLOPE * fminf(tw, 0.f);
        float s = lx * av.x + ly * av.y + lz * av.z + lw * av.w;
        s += __shfl_xor(s, 1);
        s += __shfl_xor(s, 2);
        s += __shfl_xor(s, 4);
        float w = __expf(s);
        z += w;
        acc.x = fmaf(w, xl.x, acc.x);
        acc.y = fmaf(w, xl.y, acc.y);
        acc.z = fmaf(w, xl.z, acc.z);
        acc.w = fmaf(w, xl.w, acc.w);
    }
    const float rz = 1.f / z;
    float4 o;
    o.x = fmaf(acc.x, rz, bv.x);
    o.y = fmaf(acc.y, rz, bv.y);
    o.z = fmaf(acc.z, rz, bv.z);
    o.w = fmaf(acc.w, rz, bv.w);
    o.x = (o.x > 0.f) ? o.x : (__expf(o.x) - 1.f);
    o.y = (o.y > 0.f) ? o.y : (__expf(o.y) - 1.f);
    o.z = (o.z > 0.f) ? o.z : (__expf(o.z) - 1.f);
    o.w = (o.w > 0.f) ? o.w : (__expf(o.w) - 1.f);
    *(float4*)(out + (size_t)v * 256 + lane * 4) = o;
}

// ---------------------------------------------------------------------------
// Layer-2 edge pass: one wave per node, 4 edges per iteration.
// group = lane/16 (edge slot), li = lane%16 owns dims 4*li (64 ch, head = li/8).
// ---------------------------------------------------------------------------
__global__ __launch_bounds__(256)
void k_edge2(const float* __restrict__ XLR, const int* __restrict__ offs,
             const int* __restrict__ csr, const float* __restrict__ att,
             const float* __restrict__ bias, float* __restrict__ out, int n) {
    const int lane = threadIdx.x & 63;
    const int wid  = threadIdx.x >> 6;
    const int v = blockIdx.x * 4 + wid;
    if (v >= n) return;
    const int grp = lane >> 4, li = lane & 15;
    const float4 xr = *(const float4*)(XLR + (size_t)v * 128 + 64 + li * 4);
    const float4 av = *(const float4*)(att + li * 4);
    float z = 0.f;
    float4 acc = make_float4(0.f, 0.f, 0.f, 0.f);
    const int e0 = offs[v], e1 = offs[v + 1];
    for (int j0 = e0; j0 < e1; j0 += 4) {
        const int j = j0 + grp;
        const bool valid = (j < e1);
        const int src = valid ? csr[j] : v;
        const float4 xl = *(const float4*)(XLR + (size_t)src * 128 + li * 4);
        float tx = xl.x + xr.x, ty = xl.y + xr.y, tz = xl.z + xr.z, tw = xl.w + xr.w;
        float lx = fmaxf(tx, 0.f) + NEG_SLOPE * fminf(tx, 0.f);
        float ly = fmaxf(ty, 0.f) + NEG_SLOPE * fminf(ty, 0.f);
        float lz = fmaxf(tz, 0.f) + NEG_SLOPE * fminf(tz, 0.f);
        float lw = fmaxf(tw, 0.f) + NEG_SLOPE * fminf(tw, 0.f);
        float s = lx * av.x + ly * av.y + lz * av.z + lw * av.w;
        s += __shfl_xor(s, 1);
        s += __shfl_xor(s, 2);
        s += __shfl_xor(s, 4);
        float w = valid ? __expf(s) : 0.f;
        z += w;
        acc.x = fmaf(w, xl.x, acc.x);
        acc.y = fmaf(w, xl.y, acc.y);
        acc.z = fmaf(w, xl.z, acc.z);
        acc.w = fmaf(w, xl.w, acc.w);
    }
    // combine the 4 edge groups (butterfly over lanes 16/32 apart)
    z += __shfl_xor(z, 16); z += __shfl_xor(z, 32);
    acc.x += __shfl_xor(acc.x, 16); acc.x += __shfl_xor(acc.x, 32);
    acc.y += __shfl_xor(acc.y, 16); acc.y += __shfl_xor(acc.y, 32);
    acc.z += __shfl_xor(acc.z, 16); acc.z += __shfl_xor(acc.z, 32);
    acc.w += __shfl_xor(acc.w, 16); acc.w += __shfl_xor(acc.w, 32);
    if (grp == 0) {
        const float4 bv = *(const float4*)(bias + li * 4);
        const float rz = 1.f / z;
        float4 o;
        o.x = fmaf(acc.x, rz, bv.x);
        o.y = fmaf(acc.y, rz, bv.y);
        o.z = fmaf(acc.z, rz, bv.z);
        o.w = fmaf(acc.w, rz, bv.w);
        *(float4*)(out + (size_t)v * 64 + li * 4) = o;
    }
}

// ---------------------------------------------------------------------------
// Global mean pool: one block per graph, binary-search node range, no atomics.
// ---------------------------------------------------------------------------
__global__ __launch_bounds__(256)
void k_pool(const float* __restrict__ out2, const int* __restrict__ batch,
            float* __restrict__ hg, int n) {
    const int g = blockIdx.x;
    const int lane = threadIdx.x & 63;
    const int w = threadIdx.x >> 6;
    int lo = 0, hi = n;
    while (lo < hi) { int mid = (lo + hi) >> 1; if (batch[mid] < g) lo = mid + 1; else hi = mid; }
    const int start = lo;
    hi = n;
    while (lo < hi) { int mid = (lo + hi) >> 1; if (batch[mid] < g + 1) lo = mid + 1; else hi = mid; }
    const int end = lo;

    float s = 0.f;
    for (int v = start + w; v < end; v += 4)
        s += out2[(size_t)v * 64 + lane];
    __shared__ float red[4][64];
    red[w][lane] = s;
    __syncthreads();
    if (w == 0) {
        float tot = red[0][lane] + red[1][lane] + red[2][lane] + red[3][lane];
        float cnt = fmaxf((float)(end - start), 1.0f);
        hg[g * 64 + lane] = tot / cnt;
    }
}

// ---------------------------------------------------------------------------
// MLP head: one thread per graph
// ---------------------------------------------------------------------------
__global__ void k_mlp(const float* __restrict__ hgbuf,
                      const float* __restrict__ fc1w, const float* __restrict__ fc1b,
                      const float* __restrict__ fc2w, const float* __restrict__ fc2b,
                      const float* __restrict__ fcw,  const float* __restrict__ fcb,
                      float* __restrict__ outc, float* __restrict__ outx2) {
    int g = threadIdx.x;
    if (g >= GNUM) return;
    float hg[64];
    #pragma unroll
    for (int k = 0; k < 64; ++k) hg[k] = hgbuf[g * 64 + k];
    float x1[32];
    for (int j = 0; j < 32; ++j) {
        float s = fc1b[j];
        for (int k = 0; k < 64; ++k) s = fmaf(hg[k], fc1w[k * 32 + j], s);
        x1[j] = fmaxf(s, 0.f);
    }
    float x2[16];
    for (int j = 0; j < 16; ++j) {
        float s = fc2b[j];
        for (int k = 0; k < 32; ++k) s = fmaf(x1[k], fc2w[k * 16 + j], s);
        x2[j] = fmaxf(s, 0.f);
    }
    for (int j = 0; j < DOUT; ++j) {
        float s = fcb[j];
        for (int k = 0; k < 16; ++k) s = fmaf(x2[k], fcw[k * 10 + j], s);
        outc[g * DOUT + j] = s;
    }
    for (int j = 0; j < 16; ++j) outx2[g * 16 + j] = x2[j];
}

// ---------------------------------------------------------------------------
extern "C" void kernel_launch(void* const* d_in, const int* in_sizes, int n_in,
                              void* d_out, int out_size, void* d_ws, size_t ws_size,
                              hipStream_t stream) {
    const float* x    = (const float*)d_in[0];
    const int*   ei   = (const int*)d_in[1];
    const int*   batch= (const int*)d_in[2];
    const float* W1l  = (const float*)d_in[3];
    const float* W1r  = (const float*)d_in[4];
    const float* a1   = (const float*)d_in[5];
    const float* b1   = (const float*)d_in[6];
    const float* W2l  = (const float*)d_in[7];
    const float* W2r  = (const float*)d_in[8];
    const float* a2   = (const float*)d_in[9];
    const float* b2   = (const float*)d_in[10];
    const float* fc1w = (const float*)d_in[11];
    const float* fc1b = (const float*)d_in[12];
    const float* fc2w = (const float*)d_in[13];
    const float* fc2b = (const float*)d_in[14];
    const float* fcw  = (const float*)d_in[15];
    const float* fcb  = (const float*)d_in[16];

    const int N = in_sizes[2];          // 30000
    const int E = in_sizes[1] / 2;      // 480000
    const int ET = E + N;
    const int* esrc = ei;
    const int* edst = ei + E;
    const int NB = (N + SCAN_B - 1) / SCAN_B;

    // workspace layout
    char* ws = (char*)d_ws;
    size_t off = 0;
    float* xlr1 = (float*)(ws + off);            off += (size_t)N * 512 * 4;
    float* h1   = (float*)(ws + off);            off += (size_t)N * 256 * 4;
    int*   deg   = (int*)(ws + off);             off += ((size_t)(N + 1) * 4 + 255) & ~255ull;
    int*   cursor= (int*)(ws + off);             off += ((size_t)N * 4 + 255) & ~255ull;
    int*   csr   = (int*)(ws + off);             off += ((size_t)ET * 4 + 255) & ~255ull;
    int*   bsum  = (int*)(ws + off);             off += ((size_t)(NB + 1) * 4 + 255) & ~255ull;
    float* hgbuf = (float*)(ws + off);           off += (size_t)GNUM * 64 * 4;
    float* xlr2 = xlr1;                          // [N,128] reuse
    float* out2 = xlr1 + (size_t)N * 128;        // [N,64]
    (void)ws_size; (void)n_in; (void)out_size;

    float* outc  = (float*)d_out;
    float* outx2 = (float*)d_out + GNUM * DOUT;

    hipMemsetAsync(deg, 0, (size_t)(N + 1) * 4, stream);

    // CSR build
    int tb = 256;
    int gb = (ET + tb - 1) / tb;
    k_deg<<<gb, tb, 0, stream>>>(edst, deg, E, N);
    k_scan_partial<<<NB, SCAN_B, 0, stream>>>(deg, bsum, N);
    k_scan_bsum<<<1, 64, 0, stream>>>(bsum, NB);
    k_scan_apply<<<NB, SCAN_B, 0, stream>>>(deg, cursor, bsum, N, NB);
    k_scatter<<<gb, tb, 0, stream>>>(esrc, edst, cursor, csr, E, N);

    // Layer 1 GEMM: xl1|xr1 = x @ [W1l|W1r]
    dim3 g1((N + 63) / 64, 8);
    k_gemm_dual<<<g1, 256, 0, stream>>>(x, W1l, W1r, xlr1, N, DIN, 256);

    // Layer 1 edge pass + bias + ELU -> h1
    k_edge1<<<(N + 3) / 4, 256, 0, stream>>>(xlr1, deg, csr, a1, b1, h1, N);

    // Layer 2 GEMM: xl2|xr2 = h1 @ [W2l|W2r]
    dim3 g2((N + 63) / 64, 2);
    k_gemm_dual<<<g2, 256, 0, stream>>>(h1, W2l, W2r, xlr2, N, 256, 64);

    // Layer 2 edge pass + bias -> out2
    k_edge2<<<(N + 3) / 4, 256, 0, stream>>>(xlr2, deg, csr, a2, b2, out2, N);

    // Pool + MLP
    k_pool<<<GNUM, 256, 0, stream>>>(out2, batch, hgbuf, N);
    k_mlp<<<1, 64, 0, stream>>>(hgbuf, fc1w, fc1b, fc2w, fc2b, fcw, fcb, outc, outx2);
}

// Round 4
// 438.353 us; speedup vs baseline: 1.7264x; 1.0253x over previous
//
#include <hip/hip_runtime.h>
#include <math.h>

#define DIN 128
#define DH  32
#define H1  8
#define H2  2
#define GNUM 64
#define DOUT 10
#define NEG_SLOPE 0.2f
#define SCAN_B 512

typedef __attribute__((ext_vector_type(8))) short sv8;
typedef __attribute__((ext_vector_type(4))) short sv4;
typedef __attribute__((ext_vector_type(4))) float fv4;

static __device__ __forceinline__ unsigned short f2bf(float f) {
    unsigned int u = __float_as_uint(f);
    unsigned int r = (u + 0x7fffu + ((u >> 16) & 1u)) >> 16;
    return (unsigned short)r;
}
static __device__ __forceinline__ float bf2f(unsigned short h) {
    return __uint_as_float(((unsigned int)h) << 16);
}

// ---------------------------------------------------------------------------
// CSR build
// ---------------------------------------------------------------------------
__global__ void k_deg(const int* __restrict__ dst, int* __restrict__ deg, int E, int n) {
    int i = blockIdx.x * blockDim.x + threadIdx.x;
    if (i < E) {
        atomicAdd(&deg[dst[i]], 1);
    } else if (i < E + n) {
        atomicAdd(&deg[i - E], 1);   // self loop
    }
}

__global__ __launch_bounds__(SCAN_B)
void k_scan_partial(const int* __restrict__ deg, int* __restrict__ bsum, int n) {
    int i = blockIdx.x * SCAN_B + threadIdx.x;
    int v = (i < n) ? deg[i] : 0;
    #pragma unroll
    for (int m = 32; m >= 1; m >>= 1) v += __shfl_xor(v, m);
    __shared__ int red[SCAN_B / 64];
    if ((threadIdx.x & 63) == 0) red[threadIdx.x >> 6] = v;
    __syncthreads();
    if (threadIdx.x == 0) {
        int s = 0;
        #pragma unroll
        for (int k = 0; k < SCAN_B / 64; ++k) s += red[k];
        bsum[blockIdx.x] = s;
    }
}

__global__ void k_scan_bsum(int* __restrict__ bsum, int nb) {
    if (threadIdx.x == 0 && blockIdx.x == 0) {
        int run = 0;
        for (int k = 0; k < nb; ++k) { int t = bsum[k]; bsum[k] = run; run += t; }
        bsum[nb] = run;
    }
}

__global__ __launch_bounds__(SCAN_B)
void k_scan_apply(int* __restrict__ deg, int* __restrict__ cursor,
                  const int* __restrict__ bsum, int n, int nb) {
    __shared__ int buf[SCAN_B];
    int t = threadIdx.x, b = blockIdx.x;
    int i = b * SCAN_B + t;
    int v = (i < n) ? deg[i] : 0;
    buf[t] = v;
    __syncthreads();
    for (int o = 1; o < SCAN_B; o <<= 1) {
        int a = (t >= o) ? buf[t - o] : 0;
        __syncthreads();
        buf[t] += a;
        __syncthreads();
    }
    int excl = buf[t] - v + bsum[b];
    if (i < n) { deg[i] = excl; cursor[i] = excl; }
    if (b == 0 && t == 0) deg[n] = bsum[nb];
}

__global__ void k_scatter(const int* __restrict__ src, const int* __restrict__ dst,
                          int* __restrict__ cursor, int* __restrict__ csr_src, int E, int n) {
    int i = blockIdx.x * blockDim.x + threadIdx.x;
    if (i < E) {
        int d = dst[i];
        int pos = atomicAdd(&cursor[d], 1);
        csr_src[pos] = src[i];
    } else if (i < E + n) {
        int v = i - E;
        int pos = atomicAdd(&cursor[v], 1);
        csr_src[pos] = v;   // self loop
    }
}

// ---------------------------------------------------------------------------
// W prep: Bt[n][k] = concat(Wl, Wr) transposed, split into bf16 hi/lo
// ---------------------------------------------------------------------------
__global__ void k_prep_bt(const float* __restrict__ Wl, const float* __restrict__ Wr,
                          short* __restrict__ Bth, short* __restrict__ Btl,
                          int K, int Nh) {
    int id = blockIdx.x * blockDim.x + threadIdx.x;
    int tot = 2 * Nh * K;
    if (id >= tot) return;
    int n = id / K, k = id - n * K;
    float v = (n < Nh) ? Wl[(size_t)k * Nh + n] : Wr[(size_t)k * Nh + (n - Nh)];
    unsigned short h = f2bf(v);
    Bth[id] = (short)h;
    Btl[id] = (short)f2bf(v - bf2f(h));
}

// ---------------------------------------------------------------------------
// Split-bf16 MFMA GEMM: C[M,Ntot] = A[M,K](f32) @ Bt^T, where Bt[n][k] bf16
// hi/lo. A converted f32 -> (hi,lo) bf16 on the fly during LDS staging.
// Block: 128x128 tile, 256 threads (4 waves, 2x2 of 64x64).
// MFMA 16x16x32 bf16, C = Ah*Bh + Ah*Bl + Al*Bh (fp32 acc).
// LDS A-tile row stride 40 shorts (80 B, 16B-aligned, conflict-benign).
// ---------------------------------------------------------------------------
__global__ __launch_bounds__(256)
void k_gemm_mfma(const float* __restrict__ A, const short* __restrict__ Bth,
                 const short* __restrict__ Btl, float* __restrict__ C,
                 int M, int K, int Ntot) {
    __shared__ short Ah_s[128 * 40];
    __shared__ short Al_s[128 * 40];
    const int tid = threadIdx.x;
    const int lane = tid & 63;
    const int wid = tid >> 6;
    const int wm = wid & 1, wn = wid >> 1;
    const int m0 = blockIdx.x * 128;
    const int n0 = blockIdx.y * 128;
    const int l15 = lane & 15, q = lane >> 4;

    fv4 acc[4][4] = {};

    for (int kk = 0; kk < K; kk += 32) {
        __syncthreads();
        // stage A tile: 128 rows x 32 k (f32 -> bf16 hi/lo)
        #pragma unroll
        for (int i = 0; i < 4; ++i) {
            int idx = tid + i * 256;      // 1024 float4 slots
            int row = idx >> 3;
            int qq  = idx & 7;
            int mg  = m0 + row;
            float4 v = make_float4(0.f, 0.f, 0.f, 0.f);
            if (mg < M) v = *(const float4*)(A + (size_t)mg * K + kk + qq * 4);
            unsigned short hx = f2bf(v.x), hy = f2bf(v.y), hz = f2bf(v.z), hw = f2bf(v.w);
            sv4 hi = { (short)hx, (short)hy, (short)hz, (short)hw };
            sv4 lo = { (short)f2bf(v.x - bf2f(hx)), (short)f2bf(v.y - bf2f(hy)),
                       (short)f2bf(v.z - bf2f(hz)), (short)f2bf(v.w - bf2f(hw)) };
            *(sv4*)&Ah_s[row * 40 + qq * 4] = hi;
            *(sv4*)&Al_s[row * 40 + qq * 4] = lo;
        }
        __syncthreads();

        // B fragments straight from global (Bt is tiny, L1/L2 resident)
        sv8 bh[4], bl[4];
        #pragma unroll
        for (int fn = 0; fn < 4; ++fn) {
            int ng = n0 + wn * 64 + fn * 16 + l15;
            const short* bp = Bth + (size_t)ng * K + kk + q * 8;
            const short* lp = Btl + (size_t)ng * K + kk + q * 8;
            bh[fn] = *(const sv8*)bp;
            bl[fn] = *(const sv8*)lp;
        }
        #pragma unroll
        for (int fm = 0; fm < 4; ++fm) {
            int rl = wm * 64 + fm * 16 + l15;
            sv8 ah = *(const sv8*)&Ah_s[rl * 40 + q * 8];
            sv8 al = *(const sv8*)&Al_s[rl * 40 + q * 8];
            #pragma unroll
            for (int fn = 0; fn < 4; ++fn) {
                acc[fm][fn] = __builtin_amdgcn_mfma_f32_16x16x32_bf16(ah, bh[fn], acc[fm][fn], 0, 0, 0);
                acc[fm][fn] = __builtin_amdgcn_mfma_f32_16x16x32_bf16(ah, bl[fn], acc[fm][fn], 0, 0, 0);
                acc[fm][fn] = __builtin_amdgcn_mfma_f32_16x16x32_bf16(al, bh[fn], acc[fm][fn], 0, 0, 0);
            }
        }
    }

    // epilogue: C/D layout col = lane&15, row = quad*4 + reg
    #pragma unroll
    for (int fm = 0; fm < 4; ++fm) {
        #pragma unroll
        for (int fn = 0; fn < 4; ++fn) {
            int gc = n0 + wn * 64 + fn * 16 + l15;
            #pragma unroll
            for (int r = 0; r < 4; ++r) {
                int gr = m0 + wm * 64 + fm * 16 + q * 4 + r;
                if (gr < M) C[(size_t)gr * Ntot + gc] = acc[fm][fn][r];
            }
        }
    }
}

// ---------------------------------------------------------------------------
// Layer-1 edge pass: one wave per node, float4 per lane (256 ch).
// ---------------------------------------------------------------------------
__global__ __launch_bounds__(256)
void k_edge1(const float* __restrict__ XLR, const int* __restrict__ offs,
             const int* __restrict__ csr, const float* __restrict__ att,
             const float* __restrict__ bias, float* __restrict__ out, int n) {
    const int lane = threadIdx.x & 63;
    const int wid  = threadIdx.x >> 6;
    const int v = blockIdx.x * 4 + wid;
    if (v >= n) return;
    const float4 xr = *(const float4*)(XLR + (size_t)v * 512 + 256 + lane * 4);
    const float4 av = *(const float4*)(att + lane * 4);
    const float4 bv = *(const float4*)(bias + lane * 4);
    float z = 0.f;
    float4 acc = make_float4(0.f, 0.f, 0.f, 0.f);
    const int e0 = offs[v], e1 = offs[v + 1];
    for (int j = e0; j < e1; ++j) {
        const int src = csr[j];
        const float4 xl = *(const float4*)(XLR + (size_t)src * 512 + lane * 4);
        float tx = xl.x + xr.x, ty = xl.y + xr.y, tz = xl.z + xr.z, tw = xl.w + xr.w;
        float lx = fmaxf(tx, 0.f) + NEG_SLOPE * fminf(tx, 0.f);
        float ly = fmaxf(ty, 0.f) + NEG_SLOPE * fminf(ty, 0.f);
        float lz = fmaxf(tz, 0.f) + NEG_SLOPE * fminf(tz, 0.f);
        float lw = fmaxf(tw, 0.f) + NEG_SLOPE * fminf(tw, 0.f);
        float s = lx * av.x + ly * av.y + lz * av.z + lw * av.w;
        s += __shfl_xor(s, 1);
        s += __shfl_xor(s, 2);
        s += __shfl_xor(s, 4);
        float w = __expf(s);
        z += w;
        acc.x = fmaf(w, xl.x, acc.x);
        acc.y = fmaf(w, xl.y, acc.y);
        acc.z = fmaf(w, xl.z, acc.z);
        acc.w = fmaf(w, xl.w, acc.w);
    }
    const float rz = 1.f / z;
    float4 o;
    o.x = fmaf(acc.x, rz, bv.x);
    o.y = fmaf(acc.y, rz, bv.y);
    o.z = fmaf(acc.z, rz, bv.z);
    o.w = fmaf(acc.w, rz, bv.w);
    o.x = (o.x > 0.f) ? o.x : (__expf(o.x) - 1.f);
    o.y = (o.y > 0.f) ? o.y : (__expf(o.y) - 1.f);
    o.z = (o.z > 0.f) ? o.z : (__expf(o.z) - 1.f);
    o.w = (o.w > 0.f) ? o.w : (__expf(o.w) - 1.f);
    *(float4*)(out + (size_t)v * 256 + lane * 4) = o;
}

// ---------------------------------------------------------------------------
// Layer-2 edge pass: one wave per node, 4 edges per iteration.
// ---------------------------------------------------------------------------
__global__ __launch_bounds__(256)
void k_edge2(const float* __restrict__ XLR, const int* __restrict__ offs,
             const int* __restrict__ csr, const float* __restrict__ att,
             const float* __restrict__ bias, float* __restrict__ out, int n) {
    const int lane = threadIdx.x & 63;
    const int wid  = threadIdx.x >> 6;
    const int v = blockIdx.x * 4 + wid;
    if (v >= n) return;
    const int grp = lane >> 4, li = lane & 15;
    const float4 xr = *(const float4*)(XLR + (size_t)v * 128 + 64 + li * 4);
    const float4 av = *(const float4*)(att + li * 4);
    float z = 0.f;
    float4 acc = make_float4(0.f, 0.f, 0.f, 0.f);
    const int e0 = offs[v], e1 = offs[v + 1];
    for (int j0 = e0; j0 < e1; j0 += 4) {
        const int j = j0 + grp;
        const bool valid = (j < e1);
        const int src = valid ? csr[j] : v;
        const float4 xl = *(const float4*)(XLR + (size_t)src * 128 + li * 4);
        float tx = xl.x + xr.x, ty = xl.y + xr.y, tz = xl.z + xr.z, tw = xl.w + xr.w;
        float lx = fmaxf(tx, 0.f) + NEG_SLOPE * fminf(tx, 0.f);
        float ly = fmaxf(ty, 0.f) + NEG_SLOPE * fminf(ty, 0.f);
        float lz = fmaxf(tz, 0.f) + NEG_SLOPE * fminf(tz, 0.f);
        float lw = fmaxf(tw, 0.f) + NEG_SLOPE * fminf(tw, 0.f);
        float s = lx * av.x + ly * av.y + lz * av.z + lw * av.w;
        s += __shfl_xor(s, 1);
        s += __shfl_xor(s, 2);
        s += __shfl_xor(s, 4);
        float w = valid ? __expf(s) : 0.f;
        z += w;
        acc.x = fmaf(w, xl.x, acc.x);
        acc.y = fmaf(w, xl.y, acc.y);
        acc.z = fmaf(w, xl.z, acc.z);
        acc.w = fmaf(w, xl.w, acc.w);
    }
    z += __shfl_xor(z, 16); z += __shfl_xor(z, 32);
    acc.x += __shfl_xor(acc.x, 16); acc.x += __shfl_xor(acc.x, 32);
    acc.y += __shfl_xor(acc.y, 16); acc.y += __shfl_xor(acc.y, 32);
    acc.z += __shfl_xor(acc.z, 16); acc.z += __shfl_xor(acc.z, 32);
    acc.w += __shfl_xor(acc.w, 16); acc.w += __shfl_xor(acc.w, 32);
    if (grp == 0) {
        const float4 bv = *(const float4*)(bias + li * 4);
        const float rz = 1.f / z;
        float4 o;
        o.x = fmaf(acc.x, rz, bv.x);
        o.y = fmaf(acc.y, rz, bv.y);
        o.z = fmaf(acc.z, rz, bv.z);
        o.w = fmaf(acc.w, rz, bv.w);
        *(float4*)(out + (size_t)v * 64 + li * 4) = o;
    }
}

// ---------------------------------------------------------------------------
// Global mean pool: one block per graph, binary-search node range.
// ---------------------------------------------------------------------------
__global__ __launch_bounds__(256)
void k_pool(const float* __restrict__ out2, const int* __restrict__ batch,
            float* __restrict__ hg, int n) {
    const int g = blockIdx.x;
    const int lane = threadIdx.x & 63;
    const int w = threadIdx.x >> 6;
    int lo = 0, hi = n;
    while (lo < hi) { int mid = (lo + hi) >> 1; if (batch[mid] < g) lo = mid + 1; else hi = mid; }
    const int start = lo;
    hi = n;
    while (lo < hi) { int mid = (lo + hi) >> 1; if (batch[mid] < g + 1) lo = mid + 1; else hi = mid; }
    const int end = lo;

    float s = 0.f;
    for (int v = start + w; v < end; v += 4)
        s += out2[(size_t)v * 64 + lane];
    __shared__ float red[4][64];
    red[w][lane] = s;
    __syncthreads();
    if (w == 0) {
        float tot = red[0][lane] + red[1][lane] + red[2][lane] + red[3][lane];
        float cnt = fmaxf((float)(end - start), 1.0f);
        hg[g * 64 + lane] = tot / cnt;
    }
}

// ---------------------------------------------------------------------------
// MLP head
// ---------------------------------------------------------------------------
__global__ void k_mlp(const float* __restrict__ hgbuf,
                      const float* __restrict__ fc1w, const float* __restrict__ fc1b,
                      const float* __restrict__ fc2w, const float* __restrict__ fc2b,
                      const float* __restrict__ fcw,  const float* __restrict__ fcb,
                      float* __restrict__ outc, float* __restrict__ outx2) {
    int g = threadIdx.x;
    if (g >= GNUM) return;
    float hg[64];
    #pragma unroll
    for (int k = 0; k < 64; ++k) hg[k] = hgbuf[g * 64 + k];
    float x1[32];
    for (int j = 0; j < 32; ++j) {
        float s = fc1b[j];
        for (int k = 0; k < 64; ++k) s = fmaf(hg[k], fc1w[k * 32 + j], s);
        x1[j] = fmaxf(s, 0.f);
    }
    float x2[16];
    for (int j = 0; j < 16; ++j) {
        float s = fc2b[j];
        for (int k = 0; k < 32; ++k) s = fmaf(x1[k], fc2w[k * 16 + j], s);
        x2[j] = fmaxf(s, 0.f);
    }
    for (int j = 0; j < DOUT; ++j) {
        float s = fcb[j];
        for (int k = 0; k < 16; ++k) s = fmaf(x2[k], fcw[k * 10 + j], s);
        outc[g * DOUT + j] = s;
    }
    for (int j = 0; j < 16; ++j) outx2[g * 16 + j] = x2[j];
}

// ---------------------------------------------------------------------------
extern "C" void kernel_launch(void* const* d_in, const int* in_sizes, int n_in,
                              void* d_out, int out_size, void* d_ws, size_t ws_size,
                              hipStream_t stream) {
    const float* x    = (const float*)d_in[0];
    const int*   ei   = (const int*)d_in[1];
    const int*   batch= (const int*)d_in[2];
    const float* W1l  = (const float*)d_in[3];
    const float* W1r  = (const float*)d_in[4];
    const float* a1   = (const float*)d_in[5];
    const float* b1   = (const float*)d_in[6];
    const float* W2l  = (const float*)d_in[7];
    const float* W2r  = (const float*)d_in[8];
    const float* a2   = (const float*)d_in[9];
    const float* b2   = (const float*)d_in[10];
    const float* fc1w = (const float*)d_in[11];
    const float* fc1b = (const float*)d_in[12];
    const float* fc2w = (const float*)d_in[13];
    const float* fc2b = (const float*)d_in[14];
    const float* fcw  = (const float*)d_in[15];
    const float* fcb  = (const float*)d_in[16];

    const int N = in_sizes[2];          // 30000
    const int E = in_sizes[1] / 2;      // 480000
    const int ET = E + N;
    const int* esrc = ei;
    const int* edst = ei + E;
    const int NB = (N + SCAN_B - 1) / SCAN_B;

    // workspace layout
    char* ws = (char*)d_ws;
    size_t off = 0;
    float* xlr1 = (float*)(ws + off);            off += (size_t)N * 512 * 4;
    float* h1   = (float*)(ws + off);            off += (size_t)N * 256 * 4;
    int*   deg   = (int*)(ws + off);             off += ((size_t)(N + 1) * 4 + 255) & ~255ull;
    int*   cursor= (int*)(ws + off);             off += ((size_t)N * 4 + 255) & ~255ull;
    int*   csr   = (int*)(ws + off);             off += ((size_t)ET * 4 + 255) & ~255ull;
    int*   bsum  = (int*)(ws + off);             off += ((size_t)(NB + 1) * 4 + 255) & ~255ull;
    float* hgbuf = (float*)(ws + off);           off += (size_t)GNUM * 64 * 4;
    short* B1th  = (short*)(ws + off);           off += (size_t)512 * 128 * 2;
    short* B1tl  = (short*)(ws + off);           off += (size_t)512 * 128 * 2;
    short* B2th  = (short*)(ws + off);           off += (size_t)128 * 256 * 2;
    short* B2tl  = (short*)(ws + off);           off += (size_t)128 * 256 * 2;
    float* xlr2 = xlr1;                          // [N,128] reuse
    float* out2 = xlr1 + (size_t)N * 128;        // [N,64]
    (void)ws_size; (void)n_in; (void)out_size;

    float* outc  = (float*)d_out;
    float* outx2 = (float*)d_out + GNUM * DOUT;

    hipMemsetAsync(deg, 0, (size_t)(N + 1) * 4, stream);

    // CSR build
    int tb = 256;
    int gb = (ET + tb - 1) / tb;
    k_deg<<<gb, tb, 0, stream>>>(edst, deg, E, N);
    k_scan_partial<<<NB, SCAN_B, 0, stream>>>(deg, bsum, N);
    k_scan_bsum<<<1, 64, 0, stream>>>(bsum, NB);
    k_scan_apply<<<NB, SCAN_B, 0, stream>>>(deg, cursor, bsum, N, NB);
    k_scatter<<<gb, tb, 0, stream>>>(esrc, edst, cursor, csr, E, N);

    // W prep (transpose + bf16 split)
    k_prep_bt<<<(512 * 128 + 255) / 256, 256, 0, stream>>>(W1l, W1r, B1th, B1tl, DIN, 256);
    k_prep_bt<<<(128 * 256 + 255) / 256, 256, 0, stream>>>(W2l, W2r, B2th, B2tl, 256, 64);

    // Layer 1 GEMM (MFMA split-bf16): xlr1 = x @ [W1l|W1r]  (M=N, K=128, Ntot=512)
    dim3 g1((N + 127) / 128, 4);
    k_gemm_mfma<<<g1, 256, 0, stream>>>(x, B1th, B1tl, xlr1, N, DIN, 512);

    // Layer 1 edge pass + bias + ELU -> h1 (fp32)
    k_edge1<<<(N + 3) / 4, 256, 0, stream>>>(xlr1, deg, csr, a1, b1, h1, N);

    // Layer 2 GEMM (MFMA split-bf16): xlr2 = h1 @ [W2l|W2r]  (M=N, K=256, Ntot=128)
    dim3 g2((N + 127) / 128, 1);
    k_gemm_mfma<<<g2, 256, 0, stream>>>(h1, B2th, B2tl, xlr2, N, 256, 128);

    // Layer 2 edge pass + bias -> out2
    k_edge2<<<(N + 3) / 4, 256, 0, stream>>>(xlr2, deg, csr, a2, b2, out2, N);

    // Pool + MLP
    k_pool<<<GNUM, 256, 0, stream>>>(out2, batch, hgbuf, N);
    k_mlp<<<1, 64, 0, stream>>>(hgbuf, fc1w, fc1b, fc2w, fc2b, fcw, fcb, outc, outx2);
}

// Round 5
// 386.581 us; speedup vs baseline: 1.9576x; 1.1339x over previous
//
#include <hip/hip_runtime.h>
#include <math.h>

#define DIN 128
#define DH  32
#define H1  8
#define H2  2
#define GNUM 64
#define DOUT 10
#define NEG_SLOPE 0.2f
#define SCAN_B 512

typedef __attribute__((ext_vector_type(8))) short sv8;
typedef __attribute__((ext_vector_type(4))) short sv4;
typedef __attribute__((ext_vector_type(4))) float fv4;

static __device__ __forceinline__ unsigned short f2bf(float f) {
    unsigned int u = __float_as_uint(f);
    unsigned int r = (u + 0x7fffu + ((u >> 16) & 1u)) >> 16;
    return (unsigned short)r;
}
static __device__ __forceinline__ float bf2f(unsigned short h) {
    return __uint_as_float(((unsigned int)h) << 16);
}

// ---------------------------------------------------------------------------
// CSR build
// ---------------------------------------------------------------------------
__global__ void k_deg(const int* __restrict__ dst, int* __restrict__ deg, int E, int n) {
    int i = blockIdx.x * blockDim.x + threadIdx.x;
    if (i < E) {
        atomicAdd(&deg[dst[i]], 1);
    } else if (i < E + n) {
        atomicAdd(&deg[i - E], 1);   // self loop
    }
}

__global__ __launch_bounds__(SCAN_B)
void k_scan_partial(const int* __restrict__ deg, int* __restrict__ bsum, int n) {
    int i = blockIdx.x * SCAN_B + threadIdx.x;
    int v = (i < n) ? deg[i] : 0;
    #pragma unroll
    for (int m = 32; m >= 1; m >>= 1) v += __shfl_xor(v, m);
    __shared__ int red[SCAN_B / 64];
    if ((threadIdx.x & 63) == 0) red[threadIdx.x >> 6] = v;
    __syncthreads();
    if (threadIdx.x == 0) {
        int s = 0;
        #pragma unroll
        for (int k = 0; k < SCAN_B / 64; ++k) s += red[k];
        bsum[blockIdx.x] = s;
    }
}

__global__ void k_scan_bsum(int* __restrict__ bsum, int nb) {
    if (threadIdx.x == 0 && blockIdx.x == 0) {
        int run = 0;
        for (int k = 0; k < nb; ++k) { int t = bsum[k]; bsum[k] = run; run += t; }
        bsum[nb] = run;
    }
}

__global__ __launch_bounds__(SCAN_B)
void k_scan_apply(int* __restrict__ deg, int* __restrict__ cursor,
                  const int* __restrict__ bsum, int n, int nb) {
    __shared__ int buf[SCAN_B];
    int t = threadIdx.x, b = blockIdx.x;
    int i = b * SCAN_B + t;
    int v = (i < n) ? deg[i] : 0;
    buf[t] = v;
    __syncthreads();
    for (int o = 1; o < SCAN_B; o <<= 1) {
        int a = (t >= o) ? buf[t - o] : 0;
        __syncthreads();
        buf[t] += a;
        __syncthreads();
    }
    int excl = buf[t] - v + bsum[b];
    if (i < n) { deg[i] = excl; cursor[i] = excl; }
    if (b == 0 && t == 0) deg[n] = bsum[nb];
}

__global__ void k_scatter(const int* __restrict__ src, const int* __restrict__ dst,
                          int* __restrict__ cursor, int* __restrict__ csr_src, int E, int n) {
    int i = blockIdx.x * blockDim.x + threadIdx.x;
    if (i < E) {
        int d = dst[i];
        int pos = atomicAdd(&cursor[d], 1);
        csr_src[pos] = src[i];
    } else if (i < E + n) {
        int v = i - E;
        int pos = atomicAdd(&cursor[v], 1);
        csr_src[pos] = v;   // self loop
    }
}

// ---------------------------------------------------------------------------
// W prep: Bt[n][k] = concat(Wl, Wr) transposed, split into bf16 hi/lo
// ---------------------------------------------------------------------------
__global__ void k_prep_bt(const float* __restrict__ Wl, const float* __restrict__ Wr,
                          short* __restrict__ Bth, short* __restrict__ Btl,
                          int K, int Nh) {
    int id = blockIdx.x * blockDim.x + threadIdx.x;
    int tot = 2 * Nh * K;
    if (id >= tot) return;
    int n = id / K, k = id - n * K;
    float v = (n < Nh) ? Wl[(size_t)k * Nh + n] : Wr[(size_t)k * Nh + (n - Nh)];
    unsigned short h = f2bf(v);
    Bth[id] = (short)h;
    Btl[id] = (short)f2bf(v - bf2f(h));
}

// ---------------------------------------------------------------------------
// Split-bf16 MFMA GEMM with dual-format output:
//   cols [0, NL)        -> Cl as bf16 (row-major, width NL)
//   cols [NL, Ntot)     -> Cr as f32  (row-major, width Ntot-NL)
// A[M,K] f32 converted to bf16 hi/lo during LDS staging.
// 128x128 tile, 256 threads (4 waves, 2x2 of 64x64), MFMA 16x16x32 bf16,
// C = Ah*Bh + Ah*Bl + Al*Bh. Coalesced epilogue via LDS transpose.
// ---------------------------------------------------------------------------
__global__ __launch_bounds__(256)
void k_gemm_mfma(const float* __restrict__ A, const short* __restrict__ Bth,
                 const short* __restrict__ Btl,
                 unsigned short* __restrict__ Cl, float* __restrict__ Cr,
                 int M, int K, int Ntot, int NL) {
    __shared__ union {
        struct { short hi[128 * 40]; short lo[128 * 40]; } a;
        float c[64 * 132];
    } sm;
    const int tid = threadIdx.x;
    const int lane = tid & 63;
    const int wid = tid >> 6;
    const int wm = wid & 1, wn = wid >> 1;
    const int m0 = blockIdx.x * 128;
    const int n0 = blockIdx.y * 128;
    const int l15 = lane & 15, q = lane >> 4;

    fv4 acc[4][4] = {};

    for (int kk = 0; kk < K; kk += 32) {
        __syncthreads();
        // stage A tile: 128 rows x 32 k (f32 -> bf16 hi/lo)
        #pragma unroll
        for (int i = 0; i < 4; ++i) {
            int idx = tid + i * 256;      // 1024 float4 slots
            int row = idx >> 3;
            int qq  = idx & 7;
            int mg  = m0 + row;
            float4 v = make_float4(0.f, 0.f, 0.f, 0.f);
            if (mg < M) v = *(const float4*)(A + (size_t)mg * K + kk + qq * 4);
            unsigned short hx = f2bf(v.x), hy = f2bf(v.y), hz = f2bf(v.z), hw = f2bf(v.w);
            sv4 hi = { (short)hx, (short)hy, (short)hz, (short)hw };
            sv4 lo = { (short)f2bf(v.x - bf2f(hx)), (short)f2bf(v.y - bf2f(hy)),
                       (short)f2bf(v.z - bf2f(hz)), (short)f2bf(v.w - bf2f(hw)) };
            *(sv4*)&sm.a.hi[row * 40 + qq * 4] = hi;
            *(sv4*)&sm.a.lo[row * 40 + qq * 4] = lo;
        }
        __syncthreads();

        // B fragments straight from global (Bt is small, L2-resident)
        sv8 bh[4], bl[4];
        #pragma unroll
        for (int fn = 0; fn < 4; ++fn) {
            int ng = n0 + wn * 64 + fn * 16 + l15;
            bh[fn] = *(const sv8*)(Bth + (size_t)ng * K + kk + q * 8);
            bl[fn] = *(const sv8*)(Btl + (size_t)ng * K + kk + q * 8);
        }
        #pragma unroll
        for (int fm = 0; fm < 4; ++fm) {
            int rl = wm * 64 + fm * 16 + l15;
            sv8 ah = *(const sv8*)&sm.a.hi[rl * 40 + q * 8];
            sv8 al = *(const sv8*)&sm.a.lo[rl * 40 + q * 8];
            #pragma unroll
            for (int fn = 0; fn < 4; ++fn) {
                acc[fm][fn] = __builtin_amdgcn_mfma_f32_16x16x32_bf16(ah, bh[fn], acc[fm][fn], 0, 0, 0);
                acc[fm][fn] = __builtin_amdgcn_mfma_f32_16x16x32_bf16(ah, bl[fn], acc[fm][fn], 0, 0, 0);
                acc[fm][fn] = __builtin_amdgcn_mfma_f32_16x16x32_bf16(al, bh[fn], acc[fm][fn], 0, 0, 0);
            }
        }
    }

    // epilogue: 2 slices of 64 rows through LDS, coalesced vector writes
    const int NR = Ntot - NL;
    #pragma unroll
    for (int s = 0; s < 2; ++s) {
        __syncthreads();
        if (wm == s) {
            #pragma unroll
            for (int fm = 0; fm < 4; ++fm)
                #pragma unroll
                for (int fn = 0; fn < 4; ++fn)
                    #pragma unroll
                    for (int r = 0; r < 4; ++r)
                        sm.c[(fm * 16 + q * 4 + r) * 132 + wn * 64 + fn * 16 + l15] = acc[fm][fn][r];
        }
        __syncthreads();
        #pragma unroll
        for (int i = 0; i < 2; ++i) {
            int lr = (tid >> 3) + i * 32;
            int grow = m0 + s * 64 + lr;
            if (grow < M) {
                #pragma unroll
                for (int k4 = 0; k4 < 4; ++k4) {
                    int jj = (tid & 7) + k4 * 8;            // float4 index within 128 cols
                    float4 vv = *(float4*)&sm.c[lr * 132 + jj * 4];
                    int gcol = n0 + jj * 4;
                    if (gcol < NL) {
                        ushort4 uu;
                        uu.x = f2bf(vv.x); uu.y = f2bf(vv.y);
                        uu.z = f2bf(vv.z); uu.w = f2bf(vv.w);
                        *(ushort4*)(Cl + (size_t)grow * NL + gcol) = uu;
                    } else {
                        *(float4*)(Cr + (size_t)grow * NR + (gcol - NL)) = vv;
                    }
                }
            }
        }
    }
}

// ---------------------------------------------------------------------------
// per-edge accumulate helper (8-lane head groups: shuffles xor 1,2,4)
// ---------------------------------------------------------------------------
static __device__ __forceinline__ void edge_acc(const float4 xl, const float4 xr,
                                                const float4 av, float& z, float4& acc) {
    float tx = xl.x + xr.x, ty = xl.y + xr.y, tz = xl.z + xr.z, tw = xl.w + xr.w;
    float lx = fmaxf(tx, 0.f) + NEG_SLOPE * fminf(tx, 0.f);
    float ly = fmaxf(ty, 0.f) + NEG_SLOPE * fminf(ty, 0.f);
    float lz = fmaxf(tz, 0.f) + NEG_SLOPE * fminf(tz, 0.f);
    float lw = fmaxf(tw, 0.f) + NEG_SLOPE * fminf(tw, 0.f);
    float s = lx * av.x + ly * av.y + lz * av.z + lw * av.w;
    s += __shfl_xor(s, 1);
    s += __shfl_xor(s, 2);
    s += __shfl_xor(s, 4);
    float w = __expf(s);
    z += w;
    acc.x = fmaf(w, xl.x, acc.x);
    acc.y = fmaf(w, xl.y, acc.y);
    acc.z = fmaf(w, xl.z, acc.z);
    acc.w = fmaf(w, xl.w, acc.w);
}

static __device__ __forceinline__ float4 bfx4(const ushort4 u) {
    float4 f;
    f.x = bf2f(u.x); f.y = bf2f(u.y); f.z = bf2f(u.z); f.w = bf2f(u.w);
    return f;
}

// ---------------------------------------------------------------------------
// Layer-1 edge pass: one wave per node; xl gathered in bf16 (8 B/lane),
// xr fp32. Unrolled x2 for memory-level parallelism.
// ---------------------------------------------------------------------------
__global__ __launch_bounds__(256)
void k_edge1(const unsigned short* __restrict__ XLB, const float* __restrict__ XR,
             const int* __restrict__ offs, const int* __restrict__ csr,
             const float* __restrict__ att, const float* __restrict__ bias,
             float* __restrict__ out, int n) {
    const int lane = threadIdx.x & 63;
    const int wid  = threadIdx.x >> 6;
    const int v = blockIdx.x * 4 + wid;
    if (v >= n) return;
    const float4 xr = *(const float4*)(XR + (size_t)v * 256 + lane * 4);
    const float4 av = *(const float4*)(att + lane * 4);
    const float4 bv = *(const float4*)(bias + lane * 4);
    float z = 0.f;
    float4 acc = make_float4(0.f, 0.f, 0.f, 0.f);
    const int e0 = offs[v], e1 = offs[v + 1];
    int j = e0;
    for (; j + 2 <= e1; j += 2) {
        int s0 = csr[j], s1 = csr[j + 1];
        ushort4 u0 = *(const ushort4*)(XLB + (size_t)s0 * 256 + lane * 4);
        ushort4 u1 = *(const ushort4*)(XLB + (size_t)s1 * 256 + lane * 4);
        float4 x0 = bfx4(u0);
        float4 x1 = bfx4(u1);
        edge_acc(x0, xr, av, z, acc);
        edge_acc(x1, xr, av, z, acc);
    }
    if (j < e1) {
        int s0 = csr[j];
        ushort4 u0 = *(const ushort4*)(XLB + (size_t)s0 * 256 + lane * 4);
        edge_acc(bfx4(u0), xr, av, z, acc);
    }
    const float rz = 1.f / z;
    float4 o;
    o.x = fmaf(acc.x, rz, bv.x);
    o.y = fmaf(acc.y, rz, bv.y);
    o.z = fmaf(acc.z, rz, bv.z);
    o.w = fmaf(acc.w, rz, bv.w);
    o.x = (o.x > 0.f) ? o.x : (__expf(o.x) - 1.f);
    o.y = (o.y > 0.f) ? o.y : (__expf(o.y) - 1.f);
    o.z = (o.z > 0.f) ? o.z : (__expf(o.z) - 1.f);
    o.w = (o.w > 0.f) ? o.w : (__expf(o.w) - 1.f);
    *(float4*)(out + (size_t)v * 256 + lane * 4) = o;
}

// ---------------------------------------------------------------------------
// Layer-2 edge pass: one wave per node, 4 edges/iter (16 lanes each),
// xl gathered bf16, xr fp32.
// ---------------------------------------------------------------------------
__global__ __launch_bounds__(256)
void k_edge2(const unsigned short* __restrict__ XLB, const float* __restrict__ XR,
             const int* __restrict__ offs, const int* __restrict__ csr,
             const float* __restrict__ att, const float* __restrict__ bias,
             float* __restrict__ out, int n) {
    const int lane = threadIdx.x & 63;
    const int wid  = threadIdx.x >> 6;
    const int v = blockIdx.x * 4 + wid;
    if (v >= n) return;
    const int grp = lane >> 4, li = lane & 15;
    const float4 xr = *(const float4*)(XR + (size_t)v * 64 + li * 4);
    const float4 av = *(const float4*)(att + li * 4);
    float z = 0.f;
    float4 acc = make_float4(0.f, 0.f, 0.f, 0.f);
    const int e0 = offs[v], e1 = offs[v + 1];
    for (int j0 = e0; j0 < e1; j0 += 4) {
        const int j = j0 + grp;
        const bool valid = (j < e1);
        const int src = valid ? csr[j] : v;
        ushort4 u = *(const ushort4*)(XLB + (size_t)src * 64 + li * 4);
        float4 xl = bfx4(u);
        float tx = xl.x + xr.x, ty = xl.y + xr.y, tz = xl.z + xr.z, tw = xl.w + xr.w;
        float lx = fmaxf(tx, 0.f) + NEG_SLOPE * fminf(tx, 0.f);
        float ly = fmaxf(ty, 0.f) + NEG_SLOPE * fminf(ty, 0.f);
        float lz = fmaxf(tz, 0.f) + NEG_SLOPE * fminf(tz, 0.f);
        float lw = fmaxf(tw, 0.f) + NEG_SLOPE * fminf(tw, 0.f);
        float s = lx * av.x + ly * av.y + lz * av.z + lw * av.w;
        s += __shfl_xor(s, 1);
        s += __shfl_xor(s, 2);
        s += __shfl_xor(s, 4);
        float w = valid ? __expf(s) : 0.f;
        z += w;
        acc.x = fmaf(w, xl.x, acc.x);
        acc.y = fmaf(w, xl.y, acc.y);
        acc.z = fmaf(w, xl.z, acc.z);
        acc.w = fmaf(w, xl.w, acc.w);
    }
    z += __shfl_xor(z, 16); z += __shfl_xor(z, 32);
    acc.x += __shfl_xor(acc.x, 16); acc.x += __shfl_xor(acc.x, 32);
    acc.y += __shfl_xor(acc.y, 16); acc.y += __shfl_xor(acc.y, 32);
    acc.z += __shfl_xor(acc.z, 16); acc.z += __shfl_xor(acc.z, 32);
    acc.w += __shfl_xor(acc.w, 16); acc.w += __shfl_xor(acc.w, 32);
    if (grp == 0) {
        const float4 bv = *(const float4*)(bias + li * 4);
        const float rz = 1.f / z;
        float4 o;
        o.x = fmaf(acc.x, rz, bv.x);
        o.y = fmaf(acc.y, rz, bv.y);
        o.z = fmaf(acc.z, rz, bv.z);
        o.w = fmaf(acc.w, rz, bv.w);
        *(float4*)(out + (size_t)v * 64 + li * 4) = o;
    }
}

// ---------------------------------------------------------------------------
// Global mean pool: one block per graph, binary-search node range.
// ---------------------------------------------------------------------------
__global__ __launch_bounds__(256)
void k_pool(const float* __restrict__ out2, const int* __restrict__ batch,
            float* __restrict__ hg, int n) {
    const int g = blockIdx.x;
    const int lane = threadIdx.x & 63;
    const int w = threadIdx.x >> 6;
    int lo = 0, hi = n;
    while (lo < hi) { int mid = (lo + hi) >> 1; if (batch[mid] < g) lo = mid + 1; else hi = mid; }
    const int start = lo;
    hi = n;
    while (lo < hi) { int mid = (lo + hi) >> 1; if (batch[mid] < g + 1) lo = mid + 1; else hi = mid; }
    const int end = lo;

    float s = 0.f;
    for (int v = start + w; v < end; v += 4)
        s += out2[(size_t)v * 64 + lane];
    __shared__ float red[4][64];
    red[w][lane] = s;
    __syncthreads();
    if (w == 0) {
        float tot = red[0][lane] + red[1][lane] + red[2][lane] + red[3][lane];
        float cnt = fmaxf((float)(end - start), 1.0f);
        hg[g * 64 + lane] = tot / cnt;
    }
}

// ---------------------------------------------------------------------------
// MLP head
// ---------------------------------------------------------------------------
__global__ void k_mlp(const float* __restrict__ hgbuf,
                      const float* __restrict__ fc1w, const float* __restrict__ fc1b,
                      const float* __restrict__ fc2w, const float* __restrict__ fc2b,
                      const float* __restrict__ fcw,  const float* __restrict__ fcb,
                      float* __restrict__ outc, float* __restrict__ outx2) {
    int g = threadIdx.x;
    if (g >= GNUM) return;
    float hg[64];
    #pragma unroll
    for (int k = 0; k < 64; ++k) hg[k] = hgbuf[g * 64 + k];
    float x1[32];
    for (int j = 0; j < 32; ++j) {
        float s = fc1b[j];
        for (int k = 0; k < 64; ++k) s = fmaf(hg[k], fc1w[k * 32 + j], s);
        x1[j] = fmaxf(s, 0.f);
    }
    float x2[16];
    for (int j = 0; j < 16; ++j) {
        float s = fc2b[j];
        for (int k = 0; k < 32; ++k) s = fmaf(x1[k], fc2w[k * 16 + j], s);
        x2[j] = fmaxf(s, 0.f);
    }
    for (int j = 0; j < DOUT; ++j) {
        float s = fcb[j];
        for (int k = 0; k < 16; ++k) s = fmaf(x2[k], fcw[k * 10 + j], s);
        outc[g * DOUT + j] = s;
    }
    for (int j = 0; j < 16; ++j) outx2[g * 16 + j] = x2[j];
}

// ---------------------------------------------------------------------------
extern "C" void kernel_launch(void* const* d_in, const int* in_sizes, int n_in,
                              void* d_out, int out_size, void* d_ws, size_t ws_size,
                              hipStream_t stream) {
    const float* x    = (const float*)d_in[0];
    const int*   ei   = (const int*)d_in[1];
    const int*   batch= (const int*)d_in[2];
    const float* W1l  = (const float*)d_in[3];
    const float* W1r  = (const float*)d_in[4];
    const float* a1   = (const float*)d_in[5];
    const float* b1   = (const float*)d_in[6];
    const float* W2l  = (const float*)d_in[7];
    const float* W2r  = (const float*)d_in[8];
    const float* a2   = (const float*)d_in[9];
    const float* b2   = (const float*)d_in[10];
    const float* fc1w = (const float*)d_in[11];
    const float* fc1b = (const float*)d_in[12];
    const float* fc2w = (const float*)d_in[13];
    const float* fc2b = (const float*)d_in[14];
    const float* fcw  = (const float*)d_in[15];
    const float* fcb  = (const float*)d_in[16];

    const int N = in_sizes[2];          // 30000
    const int E = in_sizes[1] / 2;      // 480000
    const int ET = E + N;
    const int* esrc = ei;
    const int* edst = ei + E;
    const int NB = (N + SCAN_B - 1) / SCAN_B;

    // workspace layout
    char* ws = (char*)d_ws;
    size_t off = 0;
    unsigned short* xl1b = (unsigned short*)(ws + off);  off += (size_t)N * 256 * 2;  // bf16 xl1
    float* xr1  = (float*)(ws + off);            off += (size_t)N * 256 * 4;          // f32 xr1
    float* h1   = (float*)(ws + off);            off += (size_t)N * 256 * 4;
    int*   deg   = (int*)(ws + off);             off += ((size_t)(N + 1) * 4 + 255) & ~255ull;
    int*   cursor= (int*)(ws + off);             off += ((size_t)N * 4 + 255) & ~255ull;
    int*   csr   = (int*)(ws + off);             off += ((size_t)ET * 4 + 255) & ~255ull;
    int*   bsum  = (int*)(ws + off);             off += ((size_t)(NB + 1) * 4 + 255) & ~255ull;
    float* hgbuf = (float*)(ws + off);           off += (size_t)GNUM * 64 * 4;
    short* B1th  = (short*)(ws + off);           off += (size_t)512 * 128 * 2;
    short* B1tl  = (short*)(ws + off);           off += (size_t)512 * 128 * 2;
    short* B2th  = (short*)(ws + off);           off += (size_t)128 * 256 * 2;
    short* B2tl  = (short*)(ws + off);           off += (size_t)128 * 256 * 2;
    // layer-2 buffers reuse layer-1 regions (dead after edge1)
    unsigned short* xl2b = xl1b;                 // [N,64] bf16
    float* xr2  = xr1;                           // [N,64] f32
    float* out2 = xr1 + (size_t)N * 64;          // [N,64] f32 (within xr1 region)
    (void)ws_size; (void)n_in; (void)out_size;

    float* outc  = (float*)d_out;
    float* outx2 = (float*)d_out + GNUM * DOUT;

    hipMemsetAsync(deg, 0, (size_t)(N + 1) * 4, stream);

    // CSR build
    int tb = 256;
    int gb = (ET + tb - 1) / tb;
    k_deg<<<gb, tb, 0, stream>>>(edst, deg, E, N);
    k_scan_partial<<<NB, SCAN_B, 0, stream>>>(deg, bsum, N);
    k_scan_bsum<<<1, 64, 0, stream>>>(bsum, NB);
    k_scan_apply<<<NB, SCAN_B, 0, stream>>>(deg, cursor, bsum, N, NB);
    k_scatter<<<gb, tb, 0, stream>>>(esrc, edst, cursor, csr, E, N);

    // W prep (transpose + bf16 split)
    k_prep_bt<<<(512 * 128 + 255) / 256, 256, 0, stream>>>(W1l, W1r, B1th, B1tl, DIN, 256);
    k_prep_bt<<<(128 * 256 + 255) / 256, 256, 0, stream>>>(W2l, W2r, B2th, B2tl, 256, 64);

    // Layer 1 GEMM: cols 0..255 -> xl1b (bf16), 256..511 -> xr1 (f32)
    dim3 g1((N + 127) / 128, 4);
    k_gemm_mfma<<<g1, 256, 0, stream>>>(x, B1th, B1tl, xl1b, xr1, N, DIN, 512, 256);

    // Layer 1 edge pass + bias + ELU -> h1 (f32)
    k_edge1<<<(N + 3) / 4, 256, 0, stream>>>(xl1b, xr1, deg, csr, a1, b1, h1, N);

    // Layer 2 GEMM: cols 0..63 -> xl2b (bf16), 64..127 -> xr2 (f32)
    dim3 g2((N + 127) / 128, 1);
    k_gemm_mfma<<<g2, 256, 0, stream>>>(h1, B2th, B2tl, xl2b, xr2, N, 256, 128, 64);

    // Layer 2 edge pass + bias -> out2
    k_edge2<<<(N + 3) / 4, 256, 0, stream>>>(xl2b, xr2, deg, csr, a2, b2, out2, N);

    // Pool + MLP
    k_pool<<<GNUM, 256, 0, stream>>>(out2, batch, hgbuf, N);
    k_mlp<<<1, 64, 0, stream>>>(hgbuf, fc1w, fc1b, fc2w, fc2b, fcw, fcb, outc, outx2);
}

// Round 6
// 338.148 us; speedup vs baseline: 2.2380x; 1.1432x over previous
//
#include <hip/hip_runtime.h>
#include <math.h>

#define DIN 128
#define DH  32
#define H1  8
#define H2  2
#define GNUM 64
#define DOUT 10
#define NEG_SLOPE 0.2f
#define SCAN_B 512

typedef __attribute__((ext_vector_type(8))) short sv8;
typedef __attribute__((ext_vector_type(4))) short sv4;
typedef __attribute__((ext_vector_type(4))) float fv4;

static __device__ __forceinline__ unsigned short f2bf(float f) {
    unsigned int u = __float_as_uint(f);
    unsigned int r = (u + 0x7fffu + ((u >> 16) & 1u)) >> 16;
    return (unsigned short)r;
}
static __device__ __forceinline__ float bf2f(unsigned short h) {
    return __uint_as_float(((unsigned int)h) << 16);
}

// ---------------------------------------------------------------------------
// CSR build
// ---------------------------------------------------------------------------
__global__ void k_deg(const int* __restrict__ dst, int* __restrict__ deg, int E, int n) {
    int i = blockIdx.x * blockDim.x + threadIdx.x;
    if (i < E) {
        atomicAdd(&deg[dst[i]], 1);
    } else if (i < E + n) {
        atomicAdd(&deg[i - E], 1);   // self loop
    }
}

__global__ __launch_bounds__(SCAN_B)
void k_scan_partial(const int* __restrict__ deg, int* __restrict__ bsum, int n) {
    int i = blockIdx.x * SCAN_B + threadIdx.x;
    int v = (i < n) ? deg[i] : 0;
    #pragma unroll
    for (int m = 32; m >= 1; m >>= 1) v += __shfl_xor(v, m);
    __shared__ int red[SCAN_B / 64];
    if ((threadIdx.x & 63) == 0) red[threadIdx.x >> 6] = v;
    __syncthreads();
    if (threadIdx.x == 0) {
        int s = 0;
        #pragma unroll
        for (int k = 0; k < SCAN_B / 64; ++k) s += red[k];
        bsum[blockIdx.x] = s;
    }
}

__global__ void k_scan_bsum(int* __restrict__ bsum, int nb) {
    if (threadIdx.x == 0 && blockIdx.x == 0) {
        int run = 0;
        for (int k = 0; k < nb; ++k) { int t = bsum[k]; bsum[k] = run; run += t; }
        bsum[nb] = run;
    }
}

__global__ __launch_bounds__(SCAN_B)
void k_scan_apply(int* __restrict__ deg, int* __restrict__ cursor,
                  const int* __restrict__ bsum, int n, int nb) {
    __shared__ int buf[SCAN_B];
    int t = threadIdx.x, b = blockIdx.x;
    int i = b * SCAN_B + t;
    int v = (i < n) ? deg[i] : 0;
    buf[t] = v;
    __syncthreads();
    for (int o = 1; o < SCAN_B; o <<= 1) {
        int a = (t >= o) ? buf[t - o] : 0;
        __syncthreads();
        buf[t] += a;
        __syncthreads();
    }
    int excl = buf[t] - v + bsum[b];
    if (i < n) { deg[i] = excl; cursor[i] = excl; }
    if (b == 0 && t == 0) deg[n] = bsum[nb];
}

__global__ void k_scatter(const int* __restrict__ src, const int* __restrict__ dst,
                          int* __restrict__ cursor, int* __restrict__ csr_src, int E, int n) {
    int i = blockIdx.x * blockDim.x + threadIdx.x;
    if (i < E) {
        int d = dst[i];
        int pos = atomicAdd(&cursor[d], 1);
        csr_src[pos] = src[i];
    } else if (i < E + n) {
        int v = i - E;
        int pos = atomicAdd(&cursor[v], 1);
        csr_src[pos] = v;   // self loop
    }
}

// ---------------------------------------------------------------------------
// W prep: Bt[n][k] = concat(Wl, Wr) transposed, split into bf16 hi/lo
// ---------------------------------------------------------------------------
__global__ void k_prep_bt(const float* __restrict__ Wl, const float* __restrict__ Wr,
                          short* __restrict__ Bth, short* __restrict__ Btl,
                          int K, int Nh) {
    int id = blockIdx.x * blockDim.x + threadIdx.x;
    int tot = 2 * Nh * K;
    if (id >= tot) return;
    int n = id / K, k = id - n * K;
    float v = (n < Nh) ? Wl[(size_t)k * Nh + n] : Wr[(size_t)k * Nh + (n - Nh)];
    unsigned short h = f2bf(v);
    Bth[id] = (short)h;
    Btl[id] = (short)f2bf(v - bf2f(h));
}

// ---------------------------------------------------------------------------
// Split-bf16 MFMA GEMM with dual-format output:
//   cols [0, NL)  -> Cl as bf16 ; cols [NL, Ntot) -> Cr as f32
// ---------------------------------------------------------------------------
__global__ __launch_bounds__(256)
void k_gemm_mfma(const float* __restrict__ A, const short* __restrict__ Bth,
                 const short* __restrict__ Btl,
                 unsigned short* __restrict__ Cl, float* __restrict__ Cr,
                 int M, int K, int Ntot, int NL) {
    __shared__ union {
        struct { short hi[128 * 40]; short lo[128 * 40]; } a;
        float c[64 * 132];
    } sm;
    const int tid = threadIdx.x;
    const int lane = tid & 63;
    const int wid = tid >> 6;
    const int wm = wid & 1, wn = wid >> 1;
    const int m0 = blockIdx.x * 128;
    const int n0 = blockIdx.y * 128;
    const int l15 = lane & 15, q = lane >> 4;

    fv4 acc[4][4] = {};

    for (int kk = 0; kk < K; kk += 32) {
        __syncthreads();
        #pragma unroll
        for (int i = 0; i < 4; ++i) {
            int idx = tid + i * 256;
            int row = idx >> 3;
            int qq  = idx & 7;
            int mg  = m0 + row;
            float4 v = make_float4(0.f, 0.f, 0.f, 0.f);
            if (mg < M) v = *(const float4*)(A + (size_t)mg * K + kk + qq * 4);
            unsigned short hx = f2bf(v.x), hy = f2bf(v.y), hz = f2bf(v.z), hw = f2bf(v.w);
            sv4 hi = { (short)hx, (short)hy, (short)hz, (short)hw };
            sv4 lo = { (short)f2bf(v.x - bf2f(hx)), (short)f2bf(v.y - bf2f(hy)),
                       (short)f2bf(v.z - bf2f(hz)), (short)f2bf(v.w - bf2f(hw)) };
            *(sv4*)&sm.a.hi[row * 40 + qq * 4] = hi;
            *(sv4*)&sm.a.lo[row * 40 + qq * 4] = lo;
        }
        __syncthreads();

        sv8 bh[4], bl[4];
        #pragma unroll
        for (int fn = 0; fn < 4; ++fn) {
            int ng = n0 + wn * 64 + fn * 16 + l15;
            bh[fn] = *(const sv8*)(Bth + (size_t)ng * K + kk + q * 8);
            bl[fn] = *(const sv8*)(Btl + (size_t)ng * K + kk + q * 8);
        }
        #pragma unroll
        for (int fm = 0; fm < 4; ++fm) {
            int rl = wm * 64 + fm * 16 + l15;
            sv8 ah = *(const sv8*)&sm.a.hi[rl * 40 + q * 8];
            sv8 al = *(const sv8*)&sm.a.lo[rl * 40 + q * 8];
            #pragma unroll
            for (int fn = 0; fn < 4; ++fn) {
                acc[fm][fn] = __builtin_amdgcn_mfma_f32_16x16x32_bf16(ah, bh[fn], acc[fm][fn], 0, 0, 0);
                acc[fm][fn] = __builtin_amdgcn_mfma_f32_16x16x32_bf16(ah, bl[fn], acc[fm][fn], 0, 0, 0);
                acc[fm][fn] = __builtin_amdgcn_mfma_f32_16x16x32_bf16(al, bh[fn], acc[fm][fn], 0, 0, 0);
            }
        }
    }

    const int NR = Ntot - NL;
    #pragma unroll
    for (int s = 0; s < 2; ++s) {
        __syncthreads();
        if (wm == s) {
            #pragma unroll
            for (int fm = 0; fm < 4; ++fm)
                #pragma unroll
                for (int fn = 0; fn < 4; ++fn)
                    #pragma unroll
                    for (int r = 0; r < 4; ++r)
                        sm.c[(fm * 16 + q * 4 + r) * 132 + wn * 64 + fn * 16 + l15] = acc[fm][fn][r];
        }
        __syncthreads();
        #pragma unroll
        for (int i = 0; i < 2; ++i) {
            int lr = (tid >> 3) + i * 32;
            int grow = m0 + s * 64 + lr;
            if (grow < M) {
                #pragma unroll
                for (int k4 = 0; k4 < 4; ++k4) {
                    int jj = (tid & 7) + k4 * 8;
                    float4 vv = *(float4*)&sm.c[lr * 132 + jj * 4];
                    int gcol = n0 + jj * 4;
                    if (gcol < NL) {
                        ushort4 uu;
                        uu.x = f2bf(vv.x); uu.y = f2bf(vv.y);
                        uu.z = f2bf(vv.z); uu.w = f2bf(vv.w);
                        *(ushort4*)(Cl + (size_t)grow * NL + gcol) = uu;
                    } else {
                        *(float4*)(Cr + (size_t)grow * NR + (gcol - NL)) = vv;
                    }
                }
            }
        }
    }
}

// ---------------------------------------------------------------------------
// per-edge accumulate helper
// ---------------------------------------------------------------------------
static __device__ __forceinline__ void edge_acc(const float4 xl, const float4 xr,
                                                const float4 av, float& z, float4& acc) {
    float tx = xl.x + xr.x, ty = xl.y + xr.y, tz = xl.z + xr.z, tw = xl.w + xr.w;
    float lx = fmaxf(tx, 0.f) + NEG_SLOPE * fminf(tx, 0.f);
    float ly = fmaxf(ty, 0.f) + NEG_SLOPE * fminf(ty, 0.f);
    float lz = fmaxf(tz, 0.f) + NEG_SLOPE * fminf(tz, 0.f);
    float lw = fmaxf(tw, 0.f) + NEG_SLOPE * fminf(tw, 0.f);
    float s = lx * av.x + ly * av.y + lz * av.z + lw * av.w;
    s += __shfl_xor(s, 1);
    s += __shfl_xor(s, 2);
    s += __shfl_xor(s, 4);
    float w = __expf(s);
    z += w;
    acc.x = fmaf(w, xl.x, acc.x);
    acc.y = fmaf(w, xl.y, acc.y);
    acc.z = fmaf(w, xl.z, acc.z);
    acc.w = fmaf(w, xl.w, acc.w);
}

static __device__ __forceinline__ float4 bfx4(const ushort4 u) {
    float4 f;
    f.x = bf2f(u.x); f.y = bf2f(u.y); f.z = bf2f(u.z); f.w = bf2f(u.w);
    return f;
}

// ---------------------------------------------------------------------------
// Layer-1 edge pass: one wave per node; xl bf16 gather, xr fp32, x2 unroll.
// ---------------------------------------------------------------------------
__global__ __launch_bounds__(256)
void k_edge1(const unsigned short* __restrict__ XLB, const float* __restrict__ XR,
             const int* __restrict__ offs, const int* __restrict__ csr,
             const float* __restrict__ att, const float* __restrict__ bias,
             float* __restrict__ out, int n) {
    const int lane = threadIdx.x & 63;
    const int wid  = threadIdx.x >> 6;
    const int v = blockIdx.x * 4 + wid;
    if (v >= n) return;
    const float4 xr = *(const float4*)(XR + (size_t)v * 256 + lane * 4);
    const float4 av = *(const float4*)(att + lane * 4);
    const float4 bv = *(const float4*)(bias + lane * 4);
    float z = 0.f;
    float4 acc = make_float4(0.f, 0.f, 0.f, 0.f);
    const int e0 = offs[v], e1 = offs[v + 1];
    int j = e0;
    for (; j + 2 <= e1; j += 2) {
        int s0 = csr[j], s1 = csr[j + 1];
        ushort4 u0 = *(const ushort4*)(XLB + (size_t)s0 * 256 + lane * 4);
        ushort4 u1 = *(const ushort4*)(XLB + (size_t)s1 * 256 + lane * 4);
        float4 x0 = bfx4(u0);
        float4 x1 = bfx4(u1);
        edge_acc(x0, xr, av, z, acc);
        edge_acc(x1, xr, av, z, acc);
    }
    if (j < e1) {
        int s0 = csr[j];
        ushort4 u0 = *(const ushort4*)(XLB + (size_t)s0 * 256 + lane * 4);
        edge_acc(bfx4(u0), xr, av, z, acc);
    }
    const float rz = 1.f / z;
    float4 o;
    o.x = fmaf(acc.x, rz, bv.x);
    o.y = fmaf(acc.y, rz, bv.y);
    o.z = fmaf(acc.z, rz, bv.z);
    o.w = fmaf(acc.w, rz, bv.w);
    o.x = (o.x > 0.f) ? o.x : (__expf(o.x) - 1.f);
    o.y = (o.y > 0.f) ? o.y : (__expf(o.y) - 1.f);
    o.z = (o.z > 0.f) ? o.z : (__expf(o.z) - 1.f);
    o.w = (o.w > 0.f) ? o.w : (__expf(o.w) - 1.f);
    *(float4*)(out + (size_t)v * 256 + lane * 4) = o;
}

// ---------------------------------------------------------------------------
// Layer-2 edge pass: one wave per node, 4 edges/iter (16 lanes each).
// ---------------------------------------------------------------------------
__global__ __launch_bounds__(256)
void k_edge2(const unsigned short* __restrict__ XLB, const float* __restrict__ XR,
             const int* __restrict__ offs, const int* __restrict__ csr,
             const float* __restrict__ att, const float* __restrict__ bias,
             float* __restrict__ out, int n) {
    const int lane = threadIdx.x & 63;
    const int wid  = threadIdx.x >> 6;
    const int v = blockIdx.x * 4 + wid;
    if (v >= n) return;
    const int grp = lane >> 4, li = lane & 15;
    const float4 xr = *(const float4*)(XR + (size_t)v * 64 + li * 4);
    const float4 av = *(const float4*)(att + li * 4);
    float z = 0.f;
    float4 acc = make_float4(0.f, 0.f, 0.f, 0.f);
    const int e0 = offs[v], e1 = offs[v + 1];
    for (int j0 = e0; j0 < e1; j0 += 4) {
        const int j = j0 + grp;
        const bool valid = (j < e1);
        const int src = valid ? csr[j] : v;
        ushort4 u = *(const ushort4*)(XLB + (size_t)src * 64 + li * 4);
        float4 xl = bfx4(u);
        float tx = xl.x + xr.x, ty = xl.y + xr.y, tz = xl.z + xr.z, tw = xl.w + xr.w;
        float lx = fmaxf(tx, 0.f) + NEG_SLOPE * fminf(tx, 0.f);
        float ly = fmaxf(ty, 0.f) + NEG_SLOPE * fminf(ty, 0.f);
        float lz = fmaxf(tz, 0.f) + NEG_SLOPE * fminf(tz, 0.f);
        float lw = fmaxf(tw, 0.f) + NEG_SLOPE * fminf(tw, 0.f);
        float s = lx * av.x + ly * av.y + lz * av.z + lw * av.w;
        s += __shfl_xor(s, 1);
        s += __shfl_xor(s, 2);
        s += __shfl_xor(s, 4);
        float w = valid ? __expf(s) : 0.f;
        z += w;
        acc.x = fmaf(w, xl.x, acc.x);
        acc.y = fmaf(w, xl.y, acc.y);
        acc.z = fmaf(w, xl.z, acc.z);
        acc.w = fmaf(w, xl.w, acc.w);
    }
    z += __shfl_xor(z, 16); z += __shfl_xor(z, 32);
    acc.x += __shfl_xor(acc.x, 16); acc.x += __shfl_xor(acc.x, 32);
    acc.y += __shfl_xor(acc.y, 16); acc.y += __shfl_xor(acc.y, 32);
    acc.z += __shfl_xor(acc.z, 16); acc.z += __shfl_xor(acc.z, 32);
    acc.w += __shfl_xor(acc.w, 16); acc.w += __shfl_xor(acc.w, 32);
    if (grp == 0) {
        const float4 bv = *(const float4*)(bias + li * 4);
        const float rz = 1.f / z;
        float4 o;
        o.x = fmaf(acc.x, rz, bv.x);
        o.y = fmaf(acc.y, rz, bv.y);
        o.z = fmaf(acc.z, rz, bv.z);
        o.w = fmaf(acc.w, rz, bv.w);
        *(float4*)(out + (size_t)v * 64 + li * 4) = o;
    }
}

// ---------------------------------------------------------------------------
// Global mean pool: one block per graph, binary-search node range.
// ---------------------------------------------------------------------------
__global__ __launch_bounds__(256)
void k_pool(const float* __restrict__ out2, const int* __restrict__ batch,
            float* __restrict__ hg, int n) {
    const int g = blockIdx.x;
    const int lane = threadIdx.x & 63;
    const int w = threadIdx.x >> 6;
    int lo = 0, hi = n;
    while (lo < hi) { int mid = (lo + hi) >> 1; if (batch[mid] < g) lo = mid + 1; else hi = mid; }
    const int start = lo;
    hi = n;
    while (lo < hi) { int mid = (lo + hi) >> 1; if (batch[mid] < g + 1) lo = mid + 1; else hi = mid; }
    const int end = lo;

    float s = 0.f;
    for (int v = start + w; v < end; v += 4)
        s += out2[(size_t)v * 64 + lane];
    __shared__ float red[4][64];
    red[w][lane] = s;
    __syncthreads();
    if (w == 0) {
        float tot = red[0][lane] + red[1][lane] + red[2][lane] + red[3][lane];
        float cnt = fmaxf((float)(end - start), 1.0f);
        hg[g * 64 + lane] = tot / cnt;
    }
}

// ---------------------------------------------------------------------------
// MLP head: one block (64 threads) per graph; hg/x1/x2 staged in LDS.
// No per-thread arrays -> no scratch spills; weights L2-resident.
// ---------------------------------------------------------------------------
__global__ __launch_bounds__(64)
void k_mlp(const float* __restrict__ hgbuf,
           const float* __restrict__ fc1w, const float* __restrict__ fc1b,
           const float* __restrict__ fc2w, const float* __restrict__ fc2b,
           const float* __restrict__ fcw,  const float* __restrict__ fcb,
           float* __restrict__ outc, float* __restrict__ outx2) {
    const int g = blockIdx.x;
    const int t = threadIdx.x;
    __shared__ float hg_s[64];
    __shared__ float x1_s[32];
    __shared__ float x2_s[16];
    hg_s[t] = hgbuf[g * 64 + t];
    __syncthreads();
    if (t < 32) {
        float s = fc1b[t];
        #pragma unroll
        for (int k = 0; k < 64; ++k) s = fmaf(hg_s[k], fc1w[k * 32 + t], s);
        x1_s[t] = fmaxf(s, 0.f);
    }
    __syncthreads();
    if (t < 16) {
        float s = fc2b[t];
        #pragma unroll
        for (int k = 0; k < 32; ++k) s = fmaf(x1_s[k], fc2w[k * 16 + t], s);
        x2_s[t] = fmaxf(s, 0.f);
    }
    __syncthreads();
    if (t < DOUT) {
        float s = fcb[t];
        #pragma unroll
        for (int k = 0; k < 16; ++k) s = fmaf(x2_s[k], fcw[k * 10 + t], s);
        outc[g * DOUT + t] = s;
    }
    if (t < 16) outx2[g * 16 + t] = x2_s[t];
}

// ---------------------------------------------------------------------------
extern "C" void kernel_launch(void* const* d_in, const int* in_sizes, int n_in,
                              void* d_out, int out_size, void* d_ws, size_t ws_size,
                              hipStream_t stream) {
    const float* x    = (const float*)d_in[0];
    const int*   ei   = (const int*)d_in[1];
    const int*   batch= (const int*)d_in[2];
    const float* W1l  = (const float*)d_in[3];
    const float* W1r  = (const float*)d_in[4];
    const float* a1   = (const float*)d_in[5];
    const float* b1   = (const float*)d_in[6];
    const float* W2l  = (const float*)d_in[7];
    const float* W2r  = (const float*)d_in[8];
    const float* a2   = (const float*)d_in[9];
    const float* b2   = (const float*)d_in[10];
    const float* fc1w = (const float*)d_in[11];
    const float* fc1b = (const float*)d_in[12];
    const float* fc2w = (const float*)d_in[13];
    const float* fc2b = (const float*)d_in[14];
    const float* fcw  = (const float*)d_in[15];
    const float* fcb  = (const float*)d_in[16];

    const int N = in_sizes[2];          // 30000
    const int E = in_sizes[1] / 2;      // 480000
    const int ET = E + N;
    const int* esrc = ei;
    const int* edst = ei + E;
    const int NB = (N + SCAN_B - 1) / SCAN_B;

    // workspace layout
    char* ws = (char*)d_ws;
    size_t off = 0;
    unsigned short* xl1b = (unsigned short*)(ws + off);  off += (size_t)N * 256 * 2;
    float* xr1  = (float*)(ws + off);            off += (size_t)N * 256 * 4;
    float* h1   = (float*)(ws + off);            off += (size_t)N * 256 * 4;
    int*   deg   = (int*)(ws + off);             off += ((size_t)(N + 1) * 4 + 255) & ~255ull;
    int*   cursor= (int*)(ws + off);             off += ((size_t)N * 4 + 255) & ~255ull;
    int*   csr   = (int*)(ws + off);             off += ((size_t)ET * 4 + 255) & ~255ull;
    int*   bsum  = (int*)(ws + off);             off += ((size_t)(NB + 1) * 4 + 255) & ~255ull;
    float* hgbuf = (float*)(ws + off);           off += (size_t)GNUM * 64 * 4;
    short* B1th  = (short*)(ws + off);           off += (size_t)512 * 128 * 2;
    short* B1tl  = (short*)(ws + off);           off += (size_t)512 * 128 * 2;
    short* B2th  = (short*)(ws + off);           off += (size_t)128 * 256 * 2;
    short* B2tl  = (short*)(ws + off);           off += (size_t)128 * 256 * 2;
    unsigned short* xl2b = xl1b;                 // [N,64] bf16 (reuse)
    float* xr2  = xr1;                           // [N,64] f32 (reuse)
    float* out2 = xr1 + (size_t)N * 64;          // [N,64] f32
    (void)ws_size; (void)n_in; (void)out_size;

    float* outc  = (float*)d_out;
    float* outx2 = (float*)d_out + GNUM * DOUT;

    hipMemsetAsync(deg, 0, (size_t)(N + 1) * 4, stream);

    // CSR build
    int tb = 256;
    int gb = (ET + tb - 1) / tb;
    k_deg<<<gb, tb, 0, stream>>>(edst, deg, E, N);
    k_scan_partial<<<NB, SCAN_B, 0, stream>>>(deg, bsum, N);
    k_scan_bsum<<<1, 64, 0, stream>>>(bsum, NB);
    k_scan_apply<<<NB, SCAN_B, 0, stream>>>(deg, cursor, bsum, N, NB);
    k_scatter<<<gb, tb, 0, stream>>>(esrc, edst, cursor, csr, E, N);

    // W prep (transpose + bf16 split)
    k_prep_bt<<<(512 * 128 + 255) / 256, 256, 0, stream>>>(W1l, W1r, B1th, B1tl, DIN, 256);
    k_prep_bt<<<(128 * 256 + 255) / 256, 256, 0, stream>>>(W2l, W2r, B2th, B2tl, 256, 64);

    // Layer 1 GEMM: cols 0..255 -> xl1b (bf16), 256..511 -> xr1 (f32)
    dim3 g1((N + 127) / 128, 4);
    k_gemm_mfma<<<g1, 256, 0, stream>>>(x, B1th, B1tl, xl1b, xr1, N, DIN, 512, 256);

    // Layer 1 edge pass + bias + ELU -> h1 (f32)
    k_edge1<<<(N + 3) / 4, 256, 0, stream>>>(xl1b, xr1, deg, csr, a1, b1, h1, N);

    // Layer 2 GEMM: cols 0..63 -> xl2b (bf16), 64..127 -> xr2 (f32)
    dim3 g2((N + 127) / 128, 1);
    k_gemm_mfma<<<g2, 256, 0, stream>>>(h1, B2th, B2tl, xl2b, xr2, N, 256, 128, 64);

    // Layer 2 edge pass + bias -> out2
    k_edge2<<<(N + 3) / 4, 256, 0, stream>>>(xl2b, xr2, deg, csr, a2, b2, out2, N);

    // Pool + MLP
    k_pool<<<GNUM, 256, 0, stream>>>(out2, batch, hgbuf, N);
    k_mlp<<<GNUM, 64, 0, stream>>>(hgbuf, fc1w, fc1b, fc2w, fc2b, fcw, fcb, outc, outx2);
}

// Round 7
// 317.483 us; speedup vs baseline: 2.3837x; 1.0651x over previous
//
#include <hip/hip_runtime.h>
#include <math.h>

#define DIN 128
#define DH  32
#define H1  8
#define H2  2
#define GNUM 64
#define DOUT 10
#define NEG_SLOPE 0.2f
#define SCAN_B 512

typedef __attribute__((ext_vector_type(8))) short sv8;
typedef __attribute__((ext_vector_type(4))) short sv4;
typedef __attribute__((ext_vector_type(4))) float fv4;

static __device__ __forceinline__ unsigned short f2bf(float f) {
    unsigned int u = __float_as_uint(f);
    unsigned int r = (u + 0x7fffu + ((u >> 16) & 1u)) >> 16;
    return (unsigned short)r;
}
static __device__ __forceinline__ float bf2f(unsigned short h) {
    return __uint_as_float(((unsigned int)h) << 16);
}

// ---------------------------------------------------------------------------
// CSR build
// ---------------------------------------------------------------------------
__global__ void k_deg(const int* __restrict__ dst, int* __restrict__ deg, int E, int n) {
    int i = blockIdx.x * blockDim.x + threadIdx.x;
    if (i < E) {
        atomicAdd(&deg[dst[i]], 1);
    } else if (i < E + n) {
        atomicAdd(&deg[i - E], 1);   // self loop
    }
}

__global__ __launch_bounds__(SCAN_B)
void k_scan_partial(const int* __restrict__ deg, int* __restrict__ bsum, int n) {
    int i = blockIdx.x * SCAN_B + threadIdx.x;
    int v = (i < n) ? deg[i] : 0;
    #pragma unroll
    for (int m = 32; m >= 1; m >>= 1) v += __shfl_xor(v, m);
    __shared__ int red[SCAN_B / 64];
    if ((threadIdx.x & 63) == 0) red[threadIdx.x >> 6] = v;
    __syncthreads();
    if (threadIdx.x == 0) {
        int s = 0;
        #pragma unroll
        for (int k = 0; k < SCAN_B / 64; ++k) s += red[k];
        bsum[blockIdx.x] = s;
    }
}

// scan_apply with inlined block-prefix: every block wave-scans bsum[0..nb)
// (nb <= 64 here: N=30000 -> 59 partials), no serial kernel needed.
__global__ __launch_bounds__(SCAN_B)
void k_scan_apply(int* __restrict__ deg, int* __restrict__ cursor,
                  const int* __restrict__ bsum, int n, int nb) {
    __shared__ int buf[SCAN_B];
    __shared__ int pfx_s, tot_s;
    const int t = threadIdx.x, b = blockIdx.x;
    if (t < 64) {
        int v = (t < nb) ? bsum[t] : 0;
        int incl = v;
        #pragma unroll
        for (int o = 1; o < 64; o <<= 1) {
            int w = __shfl_up(incl, o);
            if (t >= o) incl += w;
        }
        int pfx = (b == 0) ? 0 : __shfl(incl, b - 1);
        int tot = __shfl(incl, nb - 1);
        if (t == 0) { pfx_s = pfx; tot_s = tot; }
    }
    int i = b * SCAN_B + t;
    int v = (i < n) ? deg[i] : 0;
    buf[t] = v;
    __syncthreads();
    for (int o = 1; o < SCAN_B; o <<= 1) {
        int a = (t >= o) ? buf[t - o] : 0;
        __syncthreads();
        buf[t] += a;
        __syncthreads();
    }
    int excl = buf[t] - v + pfx_s;
    if (i < n) { deg[i] = excl; cursor[i] = excl; }
    if (b == 0 && t == 0) deg[n] = tot_s;
}

__global__ void k_scatter(const int* __restrict__ src, const int* __restrict__ dst,
                          int* __restrict__ cursor, int* __restrict__ csr_src, int E, int n) {
    int i = blockIdx.x * blockDim.x + threadIdx.x;
    if (i < E) {
        int d = dst[i];
        int pos = atomicAdd(&cursor[d], 1);
        csr_src[pos] = src[i];
    } else if (i < E + n) {
        int v = i - E;
        int pos = atomicAdd(&cursor[v], 1);
        csr_src[pos] = v;   // self loop
    }
}

// ---------------------------------------------------------------------------
// W prep (both layers in one launch): Bt[n][k] transposed, bf16 hi/lo split
// ---------------------------------------------------------------------------
__global__ void k_prep(const float* __restrict__ W1l, const float* __restrict__ W1r,
                       const float* __restrict__ W2l, const float* __restrict__ W2r,
                       short* __restrict__ B1th, short* __restrict__ B1tl,
                       short* __restrict__ B2th, short* __restrict__ B2tl) {
    int id = blockIdx.x * blockDim.x + threadIdx.x;
    const int T1 = 512 * 128;
    const int T2 = 128 * 256;
    if (id < T1) {
        int n = id / 128, k = id - n * 128;
        float v = (n < 256) ? W1l[(size_t)k * 256 + n] : W1r[(size_t)k * 256 + (n - 256)];
        unsigned short h = f2bf(v);
        B1th[id] = (short)h;
        B1tl[id] = (short)f2bf(v - bf2f(h));
    } else if (id < T1 + T2) {
        int id2 = id - T1;
        int n = id2 / 256, k = id2 - n * 256;
        float v = (n < 64) ? W2l[(size_t)k * 64 + n] : W2r[(size_t)k * 64 + (n - 64)];
        unsigned short h = f2bf(v);
        B2th[id2] = (short)h;
        B2tl[id2] = (short)f2bf(v - bf2f(h));
    }
}

// ---------------------------------------------------------------------------
// Split-bf16 MFMA GEMM (A = f32, 3 products): layer 1
//   cols [0, NL) -> Cl bf16 ; cols [NL, Ntot) -> Cr f32
// ---------------------------------------------------------------------------
__global__ __launch_bounds__(256)
void k_gemm_mfma(const float* __restrict__ A, const short* __restrict__ Bth,
                 const short* __restrict__ Btl,
                 unsigned short* __restrict__ Cl, float* __restrict__ Cr,
                 int M, int K, int Ntot, int NL) {
    __shared__ union {
        struct { short hi[128 * 40]; short lo[128 * 40]; } a;
        float c[64 * 132];
    } sm;
    const int tid = threadIdx.x;
    const int lane = tid & 63;
    const int wid = tid >> 6;
    const int wm = wid & 1, wn = wid >> 1;
    const int m0 = blockIdx.x * 128;
    const int n0 = blockIdx.y * 128;
    const int l15 = lane & 15, q = lane >> 4;

    fv4 acc[4][4] = {};

    for (int kk = 0; kk < K; kk += 32) {
        __syncthreads();
        #pragma unroll
        for (int i = 0; i < 4; ++i) {
            int idx = tid + i * 256;
            int row = idx >> 3;
            int qq  = idx & 7;
            int mg  = m0 + row;
            float4 v = make_float4(0.f, 0.f, 0.f, 0.f);
            if (mg < M) v = *(const float4*)(A + (size_t)mg * K + kk + qq * 4);
            unsigned short hx = f2bf(v.x), hy = f2bf(v.y), hz = f2bf(v.z), hw = f2bf(v.w);
            sv4 hi = { (short)hx, (short)hy, (short)hz, (short)hw };
            sv4 lo = { (short)f2bf(v.x - bf2f(hx)), (short)f2bf(v.y - bf2f(hy)),
                       (short)f2bf(v.z - bf2f(hz)), (short)f2bf(v.w - bf2f(hw)) };
            *(sv4*)&sm.a.hi[row * 40 + qq * 4] = hi;
            *(sv4*)&sm.a.lo[row * 40 + qq * 4] = lo;
        }
        __syncthreads();

        sv8 bh[4], bl[4];
        #pragma unroll
        for (int fn = 0; fn < 4; ++fn) {
            int ng = n0 + wn * 64 + fn * 16 + l15;
            bh[fn] = *(const sv8*)(Bth + (size_t)ng * K + kk + q * 8);
            bl[fn] = *(const sv8*)(Btl + (size_t)ng * K + kk + q * 8);
        }
        #pragma unroll
        for (int fm = 0; fm < 4; ++fm) {
            int rl = wm * 64 + fm * 16 + l15;
            sv8 ah = *(const sv8*)&sm.a.hi[rl * 40 + q * 8];
            sv8 al = *(const sv8*)&sm.a.lo[rl * 40 + q * 8];
            #pragma unroll
            for (int fn = 0; fn < 4; ++fn) {
                acc[fm][fn] = __builtin_amdgcn_mfma_f32_16x16x32_bf16(ah, bh[fn], acc[fm][fn], 0, 0, 0);
                acc[fm][fn] = __builtin_amdgcn_mfma_f32_16x16x32_bf16(ah, bl[fn], acc[fm][fn], 0, 0, 0);
                acc[fm][fn] = __builtin_amdgcn_mfma_f32_16x16x32_bf16(al, bh[fn], acc[fm][fn], 0, 0, 0);
            }
        }
    }

    const int NR = Ntot - NL;
    #pragma unroll
    for (int s = 0; s < 2; ++s) {
        __syncthreads();
        if (wm == s) {
            #pragma unroll
            for (int fm = 0; fm < 4; ++fm)
                #pragma unroll
                for (int fn = 0; fn < 4; ++fn)
                    #pragma unroll
                    for (int r = 0; r < 4; ++r)
                        sm.c[(fm * 16 + q * 4 + r) * 132 + wn * 64 + fn * 16 + l15] = acc[fm][fn][r];
        }
        __syncthreads();
        #pragma unroll
        for (int i = 0; i < 2; ++i) {
            int lr = (tid >> 3) + i * 32;
            int grow = m0 + s * 64 + lr;
            if (grow < M) {
                #pragma unroll
                for (int k4 = 0; k4 < 4; ++k4) {
                    int jj = (tid & 7) + k4 * 8;
                    float4 vv = *(float4*)&sm.c[lr * 132 + jj * 4];
                    int gcol = n0 + jj * 4;
                    if (gcol < NL) {
                        ushort4 uu;
                        uu.x = f2bf(vv.x); uu.y = f2bf(vv.y);
                        uu.z = f2bf(vv.z); uu.w = f2bf(vv.w);
                        *(ushort4*)(Cl + (size_t)grow * NL + gcol) = uu;
                    } else {
                        *(float4*)(Cr + (size_t)grow * NR + (gcol - NL)) = vv;
                    }
                }
            }
        }
    }
}

// ---------------------------------------------------------------------------
// bf16-A MFMA GEMM (A already bf16, 2 products): layer 2 (A = h1 bf16)
// ---------------------------------------------------------------------------
__global__ __launch_bounds__(256)
void k_gemm_mfma_bf(const unsigned short* __restrict__ A, const short* __restrict__ Bth,
                    const short* __restrict__ Btl,
                    unsigned short* __restrict__ Cl, float* __restrict__ Cr,
                    int M, int K, int Ntot, int NL) {
    __shared__ union {
        short a[128 * 40];
        float c[64 * 132];
    } sm;
    const int tid = threadIdx.x;
    const int lane = tid & 63;
    const int wid = tid >> 6;
    const int wm = wid & 1, wn = wid >> 1;
    const int m0 = blockIdx.x * 128;
    const int n0 = blockIdx.y * 128;
    const int l15 = lane & 15, q = lane >> 4;

    fv4 acc[4][4] = {};

    for (int kk = 0; kk < K; kk += 32) {
        __syncthreads();
        #pragma unroll
        for (int i = 0; i < 2; ++i) {
            int idx = tid + i * 256;      // 512 chunks of 8 shorts
            int row = idx >> 2;
            int qq  = idx & 3;
            int mg  = m0 + row;
            sv8 v = { 0, 0, 0, 0, 0, 0, 0, 0 };
            if (mg < M) v = *(const sv8*)(A + (size_t)mg * K + kk + qq * 8);
            *(sv8*)&sm.a[row * 40 + qq * 8] = v;
        }
        __syncthreads();

        sv8 bh[4], bl[4];
        #pragma unroll
        for (int fn = 0; fn < 4; ++fn) {
            int ng = n0 + wn * 64 + fn * 16 + l15;
            bh[fn] = *(const sv8*)(Bth + (size_t)ng * K + kk + q * 8);
            bl[fn] = *(const sv8*)(Btl + (size_t)ng * K + kk + q * 8);
        }
        #pragma unroll
        for (int fm = 0; fm < 4; ++fm) {
            int rl = wm * 64 + fm * 16 + l15;
            sv8 ah = *(const sv8*)&sm.a[rl * 40 + q * 8];
            #pragma unroll
            for (int fn = 0; fn < 4; ++fn) {
                acc[fm][fn] = __builtin_amdgcn_mfma_f32_16x16x32_bf16(ah, bh[fn], acc[fm][fn], 0, 0, 0);
                acc[fm][fn] = __builtin_amdgcn_mfma_f32_16x16x32_bf16(ah, bl[fn], acc[fm][fn], 0, 0, 0);
            }
        }
    }

    const int NR = Ntot - NL;
    #pragma unroll
    for (int s = 0; s < 2; ++s) {
        __syncthreads();
        if (wm == s) {
            #pragma unroll
            for (int fm = 0; fm < 4; ++fm)
                #pragma unroll
                for (int fn = 0; fn < 4; ++fn)
                    #pragma unroll
                    for (int r = 0; r < 4; ++r)
                        sm.c[(fm * 16 + q * 4 + r) * 132 + wn * 64 + fn * 16 + l15] = acc[fm][fn][r];
        }
        __syncthreads();
        #pragma unroll
        for (int i = 0; i < 2; ++i) {
            int lr = (tid >> 3) + i * 32;
            int grow = m0 + s * 64 + lr;
            if (grow < M) {
                #pragma unroll
                for (int k4 = 0; k4 < 4; ++k4) {
                    int jj = (tid & 7) + k4 * 8;
                    float4 vv = *(float4*)&sm.c[lr * 132 + jj * 4];
                    int gcol = n0 + jj * 4;
                    if (gcol < NL) {
                        ushort4 uu;
                        uu.x = f2bf(vv.x); uu.y = f2bf(vv.y);
                        uu.z = f2bf(vv.z); uu.w = f2bf(vv.w);
                        *(ushort4*)(Cl + (size_t)grow * NL + gcol) = uu;
                    } else {
                        *(float4*)(Cr + (size_t)grow * NR + (gcol - NL)) = vv;
                    }
                }
            }
        }
    }
}

// ---------------------------------------------------------------------------
// per-edge accumulate helper
// ---------------------------------------------------------------------------
static __device__ __forceinline__ void edge_acc(const float4 xl, const float4 xr,
                                                const float4 av, float& z, float4& acc) {
    float tx = xl.x + xr.x, ty = xl.y + xr.y, tz = xl.z + xr.z, tw = xl.w + xr.w;
    float lx = fmaxf(tx, 0.f) + NEG_SLOPE * fminf(tx, 0.f);
    float ly = fmaxf(ty, 0.f) + NEG_SLOPE * fminf(ty, 0.f);
    float lz = fmaxf(tz, 0.f) + NEG_SLOPE * fminf(tz, 0.f);
    float lw = fmaxf(tw, 0.f) + NEG_SLOPE * fminf(tw, 0.f);
    float s = lx * av.x + ly * av.y + lz * av.z + lw * av.w;
    s += __shfl_xor(s, 1);
    s += __shfl_xor(s, 2);
    s += __shfl_xor(s, 4);
    float w = __expf(s);
    z += w;
    acc.x = fmaf(w, xl.x, acc.x);
    acc.y = fmaf(w, xl.y, acc.y);
    acc.z = fmaf(w, xl.z, acc.z);
    acc.w = fmaf(w, xl.w, acc.w);
}

static __device__ __forceinline__ float4 bfx4(const ushort4 u) {
    float4 f;
    f.x = bf2f(u.x); f.y = bf2f(u.y); f.z = bf2f(u.z); f.w = bf2f(u.w);
    return f;
}

// ---------------------------------------------------------------------------
// Layer-1 edge pass: one wave per node; xl bf16 gather, xr fp32, x4 unroll.
// Output h1 written as bf16 (feeds bf16-A layer-2 GEMM directly).
// ---------------------------------------------------------------------------
__global__ __launch_bounds__(256)
void k_edge1(const unsigned short* __restrict__ XLB, const float* __restrict__ XR,
             const int* __restrict__ offs, const int* __restrict__ csr,
             const float* __restrict__ att, const float* __restrict__ bias,
             unsigned short* __restrict__ out, int n) {
    const int lane = threadIdx.x & 63;
    const int wid  = threadIdx.x >> 6;
    const int v = blockIdx.x * 4 + wid;
    if (v >= n) return;
    const float4 xr = *(const float4*)(XR + (size_t)v * 256 + lane * 4);
    const float4 av = *(const float4*)(att + lane * 4);
    const float4 bv = *(const float4*)(bias + lane * 4);
    float z = 0.f;
    float4 acc = make_float4(0.f, 0.f, 0.f, 0.f);
    const int e0 = offs[v], e1 = offs[v + 1];
    int j = e0;
    for (; j + 4 <= e1; j += 4) {
        int s0 = csr[j], s1 = csr[j + 1], s2 = csr[j + 2], s3 = csr[j + 3];
        ushort4 u0 = *(const ushort4*)(XLB + (size_t)s0 * 256 + lane * 4);
        ushort4 u1 = *(const ushort4*)(XLB + (size_t)s1 * 256 + lane * 4);
        ushort4 u2 = *(const ushort4*)(XLB + (size_t)s2 * 256 + lane * 4);
        ushort4 u3 = *(const ushort4*)(XLB + (size_t)s3 * 256 + lane * 4);
        edge_acc(bfx4(u0), xr, av, z, acc);
        edge_acc(bfx4(u1), xr, av, z, acc);
        edge_acc(bfx4(u2), xr, av, z, acc);
        edge_acc(bfx4(u3), xr, av, z, acc);
    }
    for (; j < e1; ++j) {
        int s0 = csr[j];
        ushort4 u0 = *(const ushort4*)(XLB + (size_t)s0 * 256 + lane * 4);
        edge_acc(bfx4(u0), xr, av, z, acc);
    }
    const float rz = 1.f / z;
    float4 o;
    o.x = fmaf(acc.x, rz, bv.x);
    o.y = fmaf(acc.y, rz, bv.y);
    o.z = fmaf(acc.z, rz, bv.z);
    o.w = fmaf(acc.w, rz, bv.w);
    o.x = (o.x > 0.f) ? o.x : (__expf(o.x) - 1.f);
    o.y = (o.y > 0.f) ? o.y : (__expf(o.y) - 1.f);
    o.z = (o.z > 0.f) ? o.z : (__expf(o.z) - 1.f);
    o.w = (o.w > 0.f) ? o.w : (__expf(o.w) - 1.f);
    ushort4 hv;
    hv.x = f2bf(o.x); hv.y = f2bf(o.y); hv.z = f2bf(o.z); hv.w = f2bf(o.w);
    *(ushort4*)(out + (size_t)v * 256 + lane * 4) = hv;
}

// ---------------------------------------------------------------------------
// Layer-2 edge pass: one wave per node, 4 edges/iter (16 lanes each).
// ---------------------------------------------------------------------------
__global__ __launch_bounds__(256)
void k_edge2(const unsigned short* __restrict__ XLB, const float* __restrict__ XR,
             const int* __restrict__ offs, const int* __restrict__ csr,
             const float* __restrict__ att, const float* __restrict__ bias,
             float* __restrict__ out, int n) {
    const int lane = threadIdx.x & 63;
    const int wid  = threadIdx.x >> 6;
    const int v = blockIdx.x * 4 + wid;
    if (v >= n) return;
    const int grp = lane >> 4, li = lane & 15;
    const float4 xr = *(const float4*)(XR + (size_t)v * 64 + li * 4);
    const float4 av = *(const float4*)(att + li * 4);
    float z = 0.f;
    float4 acc = make_float4(0.f, 0.f, 0.f, 0.f);
    const int e0 = offs[v], e1 = offs[v + 1];
    for (int j0 = e0; j0 < e1; j0 += 4) {
        const int j = j0 + grp;
        const bool valid = (j < e1);
        const int src = valid ? csr[j] : v;
        ushort4 u = *(const ushort4*)(XLB + (size_t)src * 64 + li * 4);
        float4 xl = bfx4(u);
        float tx = xl.x + xr.x, ty = xl.y + xr.y, tz = xl.z + xr.z, tw = xl.w + xr.w;
        float lx = fmaxf(tx, 0.f) + NEG_SLOPE * fminf(tx, 0.f);
        float ly = fmaxf(ty, 0.f) + NEG_SLOPE * fminf(ty, 0.f);
        float lz = fmaxf(tz, 0.f) + NEG_SLOPE * fminf(tz, 0.f);
        float lw = fmaxf(tw, 0.f) + NEG_SLOPE * fminf(tw, 0.f);
        float s = lx * av.x + ly * av.y + lz * av.z + lw * av.w;
        s += __shfl_xor(s, 1);
        s += __shfl_xor(s, 2);
        s += __shfl_xor(s, 4);
        float w = valid ? __expf(s) : 0.f;
        z += w;
        acc.x = fmaf(w, xl.x, acc.x);
        acc.y = fmaf(w, xl.y, acc.y);
        acc.z = fmaf(w, xl.z, acc.z);
        acc.w = fmaf(w, xl.w, acc.w);
    }
    z += __shfl_xor(z, 16); z += __shfl_xor(z, 32);
    acc.x += __shfl_xor(acc.x, 16); acc.x += __shfl_xor(acc.x, 32);
    acc.y += __shfl_xor(acc.y, 16); acc.y += __shfl_xor(acc.y, 32);
    acc.z += __shfl_xor(acc.z, 16); acc.z += __shfl_xor(acc.z, 32);
    acc.w += __shfl_xor(acc.w, 16); acc.w += __shfl_xor(acc.w, 32);
    if (grp == 0) {
        const float4 bv = *(const float4*)(bias + li * 4);
        const float rz = 1.f / z;
        float4 o;
        o.x = fmaf(acc.x, rz, bv.x);
        o.y = fmaf(acc.y, rz, bv.y);
        o.z = fmaf(acc.z, rz, bv.z);
        o.w = fmaf(acc.w, rz, bv.w);
        *(float4*)(out + (size_t)v * 64 + li * 4) = o;
    }
}

// ---------------------------------------------------------------------------
// Fused mean-pool + MLP head: one block per graph.
// ---------------------------------------------------------------------------
__global__ __launch_bounds__(256)
void k_pool_mlp(const float* __restrict__ out2, const int* __restrict__ batch,
                const float* __restrict__ fc1w, const float* __restrict__ fc1b,
                const float* __restrict__ fc2w, const float* __restrict__ fc2b,
                const float* __restrict__ fcw,  const float* __restrict__ fcb,
                float* __restrict__ outc, float* __restrict__ outx2, int n) {
    const int g = blockIdx.x;
    const int t = threadIdx.x;
    const int lane = t & 63;
    const int w = t >> 6;
    __shared__ float red[4][64];
    __shared__ float hg_s[64];
    __shared__ float x1_s[32];
    __shared__ float x2_s[16];

    int lo = 0, hi = n;
    while (lo < hi) { int mid = (lo + hi) >> 1; if (batch[mid] < g) lo = mid + 1; else hi = mid; }
    const int start = lo;
    hi = n;
    while (lo < hi) { int mid = (lo + hi) >> 1; if (batch[mid] < g + 1) lo = mid + 1; else hi = mid; }
    const int end = lo;

    float s = 0.f;
    for (int v = start + w; v < end; v += 4)
        s += out2[(size_t)v * 64 + lane];
    red[w][lane] = s;
    __syncthreads();
    if (w == 0) {
        float tot = red[0][lane] + red[1][lane] + red[2][lane] + red[3][lane];
        float cnt = fmaxf((float)(end - start), 1.0f);
        hg_s[lane] = tot / cnt;
    }
    __syncthreads();
    if (t < 32) {
        float a = fc1b[t];
        #pragma unroll
        for (int k = 0; k < 64; ++k) a = fmaf(hg_s[k], fc1w[k * 32 + t], a);
        x1_s[t] = fmaxf(a, 0.f);
    }
    __syncthreads();
    if (t < 16) {
        float a = fc2b[t];
        #pragma unroll
        for (int k = 0; k < 32; ++k) a = fmaf(x1_s[k], fc2w[k * 16 + t], a);
        x2_s[t] = fmaxf(a, 0.f);
    }
    __syncthreads();
    if (t < DOUT) {
        float a = fcb[t];
        #pragma unroll
        for (int k = 0; k < 16; ++k) a = fmaf(x2_s[k], fcw[k * 10 + t], a);
        outc[g * DOUT + t] = a;
    }
    if (t < 16) outx2[g * 16 + t] = x2_s[t];
}

// ---------------------------------------------------------------------------
extern "C" void kernel_launch(void* const* d_in, const int* in_sizes, int n_in,
                              void* d_out, int out_size, void* d_ws, size_t ws_size,
                              hipStream_t stream) {
    const float* x    = (const float*)d_in[0];
    const int*   ei   = (const int*)d_in[1];
    const int*   batch= (const int*)d_in[2];
    const float* W1l  = (const float*)d_in[3];
    const float* W1r  = (const float*)d_in[4];
    const float* a1   = (const float*)d_in[5];
    const float* b1   = (const float*)d_in[6];
    const float* W2l  = (const float*)d_in[7];
    const float* W2r  = (const float*)d_in[8];
    const float* a2   = (const float*)d_in[9];
    const float* b2   = (const float*)d_in[10];
    const float* fc1w = (const float*)d_in[11];
    const float* fc1b = (const float*)d_in[12];
    const float* fc2w = (const float*)d_in[13];
    const float* fc2b = (const float*)d_in[14];
    const float* fcw  = (const float*)d_in[15];
    const float* fcb  = (const float*)d_in[16];

    const int N = in_sizes[2];          // 30000
    const int E = in_sizes[1] / 2;      // 480000
    const int ET = E + N;
    const int* esrc = ei;
    const int* edst = ei + E;
    const int NB = (N + SCAN_B - 1) / SCAN_B;   // 59 (<= 64 required by k_scan_apply)

    // workspace layout
    char* ws = (char*)d_ws;
    size_t off = 0;
    unsigned short* xl1b = (unsigned short*)(ws + off);  off += (size_t)N * 256 * 2;
    float* xr1  = (float*)(ws + off);            off += (size_t)N * 256 * 4;
    unsigned short* h1b = (unsigned short*)(ws + off);   off += (size_t)N * 256 * 2;
    int*   deg   = (int*)(ws + off);             off += ((size_t)(N + 1) * 4 + 255) & ~255ull;
    int*   cursor= (int*)(ws + off);             off += ((size_t)N * 4 + 255) & ~255ull;
    int*   csr   = (int*)(ws + off);             off += ((size_t)ET * 4 + 255) & ~255ull;
    int*   bsum  = (int*)(ws + off);             off += ((size_t)(NB + 1) * 4 + 255) & ~255ull;
    short* B1th  = (short*)(ws + off);           off += (size_t)512 * 128 * 2;
    short* B1tl  = (short*)(ws + off);           off += (size_t)512 * 128 * 2;
    short* B2th  = (short*)(ws + off);           off += (size_t)128 * 256 * 2;
    short* B2tl  = (short*)(ws + off);           off += (size_t)128 * 256 * 2;
    unsigned short* xl2b = xl1b;                 // [N,64] bf16 (reuse)
    float* xr2  = xr1;                           // [N,64] f32 (reuse)
    float* out2 = xr1 + (size_t)N * 64;          // [N,64] f32
    (void)ws_size; (void)n_in; (void)out_size;

    float* outc  = (float*)d_out;
    float* outx2 = (float*)d_out + GNUM * DOUT;

    hipMemsetAsync(deg, 0, (size_t)(N + 1) * 4, stream);

    // CSR build
    int tb = 256;
    int gb = (ET + tb - 1) / tb;
    k_deg<<<gb, tb, 0, stream>>>(edst, deg, E, N);
    k_scan_partial<<<NB, SCAN_B, 0, stream>>>(deg, bsum, N);
    k_scan_apply<<<NB, SCAN_B, 0, stream>>>(deg, cursor, bsum, N, NB);
    k_scatter<<<gb, tb, 0, stream>>>(esrc, edst, cursor, csr, E, N);

    // W prep (both layers, one launch)
    k_prep<<<(512 * 128 + 128 * 256 + 255) / 256, 256, 0, stream>>>(
        W1l, W1r, W2l, W2r, B1th, B1tl, B2th, B2tl);

    // Layer 1 GEMM: cols 0..255 -> xl1b (bf16), 256..511 -> xr1 (f32)
    dim3 g1((N + 127) / 128, 4);
    k_gemm_mfma<<<g1, 256, 0, stream>>>(x, B1th, B1tl, xl1b, xr1, N, DIN, 512, 256);

    // Layer 1 edge pass + bias + ELU -> h1b (bf16)
    k_edge1<<<(N + 3) / 4, 256, 0, stream>>>(xl1b, xr1, deg, csr, a1, b1, h1b, N);

    // Layer 2 GEMM (bf16 A, 2 products): cols 0..63 -> xl2b, 64..127 -> xr2
    dim3 g2((N + 127) / 128, 1);
    k_gemm_mfma_bf<<<g2, 256, 0, stream>>>(h1b, B2th, B2tl, xl2b, xr2, N, 256, 128, 64);

    // Layer 2 edge pass + bias -> out2
    k_edge2<<<(N + 3) / 4, 256, 0, stream>>>(xl2b, xr2, deg, csr, a2, b2, out2, N);

    // Fused pool + MLP
    k_pool_mlp<<<GNUM, 256, 0, stream>>>(out2, batch, fc1w, fc1b, fc2w, fc2b,
                                         fcw, fcb, outc, outx2, N);
}